// Round 1
// baseline (4978.794 us; speedup 1.0000x reference)
//
#include <hip/hip_runtime.h>
#include <math.h>

#define E_TOT 100000
#define ET 16
constexpr int NS = 128, NV = 64, DIM = 320;

constexpr float SC_S_SCALE = 0.022097086912079608f;  // 1/sqrt(128*16)
constexpr float SC_V_SCALE = 0.03125f;               // 1/32
constexpr float INV_SQRT128 = 0.08838834764831845f;
constexpr float INV_8 = 0.125f;
constexpr float INV_S384 = 0.05103103630798288f;     // 1/sqrt(384)
constexpr float INV_24 = 0.041666666666666664f;      // 1/sqrt(576)
constexpr float INV_S192 = 0.07216878364870323f;     // 1/sqrt(192)
constexpr float RSQRT2 = 0.7071067811865476f;

__device__ __forceinline__ float sigmoidf_(float x) { return 1.0f / (1.0f + __expf(-x)); }
__device__ __forceinline__ float siluf_(float x) { return x * sigmoidf_(x); }

// ---------------- K1: skip-connection einsums sc_s, sc_v -> d_out ----------------
__global__ __launch_bounds__(256) void k_sc(
    const float* __restrict__ edge_fea, const float* __restrict__ ohp,
    const float* __restrict__ Wsc_s, const float* __restrict__ Wsc_v,
    float* __restrict__ out) {
  __shared__ float esL[128][ET];
  __shared__ float evL[192][ET];
  __shared__ float ohL[16][ET];
  __shared__ float esp[128][ET];   // es[v]*oh[s] for current s
  __shared__ float evp[192][ET];   // ev[v,m]*oh[s] for current s
  const int t = threadIdx.x;
  const int e0 = blockIdx.x * ET;

  for (int o = t; o < ET * DIM; o += 256) {
    int e = o / DIM, c = o % DIM;
    float x = edge_fea[(size_t)(e0 + e) * DIM + c];
    if (c < NS) esL[c][e] = x; else evL[c - NS][e] = x;
  }
  for (int o = t; o < ET * 16; o += 256) {
    int e = o >> 4, s = o & 15;
    ohL[s][e] = ohp[(size_t)(e0 + e) * 16 + s];
  }
  __syncthreads();

  const int u = t & 127, eh = t >> 7;       // sc_s: 8 edges each
  const int uv = t & 63, r = t >> 6;        // sc_v: 4 edges each, all 3 m
  float acc[8] = {0, 0, 0, 0, 0, 0, 0, 0};
  float accv[3][4] = {{0, 0, 0, 0}, {0, 0, 0, 0}, {0, 0, 0, 0}};

  for (int s = 0; s < 16; ++s) {
    for (int o = t; o < 128 * ET; o += 256) { int v = o >> 4, e = o & 15; esp[v][e] = esL[v][e] * ohL[s][e]; }
    for (int o = t; o < 192 * ET; o += 256) { int v = o >> 4, e = o & 15; evp[v][e] = evL[v][e] * ohL[s][e]; }
    __syncthreads();

    const float* W = Wsc_s + (size_t)s * 128 + u;
    #pragma unroll 4
    for (int v = 0; v < 128; ++v) {
      float w = W[(size_t)v * 2048];
      const float4 a0 = *(const float4*)&esp[v][eh * 8];
      const float4 a1 = *(const float4*)&esp[v][eh * 8 + 4];
      acc[0] += a0.x * w; acc[1] += a0.y * w; acc[2] += a0.z * w; acc[3] += a0.w * w;
      acc[4] += a1.x * w; acc[5] += a1.y * w; acc[6] += a1.z * w; acc[7] += a1.w * w;
    }
    const float* Wv = Wsc_v + (size_t)s * 64 + uv;
    #pragma unroll 2
    for (int v = 0; v < 64; ++v) {
      float w = Wv[(size_t)v * 1024];
      #pragma unroll
      for (int m = 0; m < 3; ++m) {
        const float4 a = *(const float4*)&evp[v * 3 + m][r * 4];
        accv[m][0] += a.x * w; accv[m][1] += a.y * w; accv[m][2] += a.z * w; accv[m][3] += a.w * w;
      }
    }
    __syncthreads();
  }

  #pragma unroll
  for (int q = 0; q < 8; ++q)
    out[(size_t)(e0 + eh * 8 + q) * DIM + u] = acc[q] * SC_S_SCALE;
  #pragma unroll
  for (int m = 0; m < 3; ++m)
    #pragma unroll
    for (int q = 0; q < 4; ++q)
      out[(size_t)(e0 + r * 4 + q) * DIM + NS + uv * 3 + m] = accv[m][q] * SC_V_SCALE;
}

// ---------------- K2: fused main chain, accumulates onto sc in d_out ----------------
__global__ __launch_bounds__(512, 1) void k_main(
    const float* __restrict__ node_fea, const float* __restrict__ edge_sh,
    const float* __restrict__ edge_fea, const float* __restrict__ elen,
    const int* __restrict__ eidx,
    const float* __restrict__ Wpre0, const float* __restrict__ bpre0,
    const float* __restrict__ Wpre1,
    const float* __restrict__ Wss, const float* __restrict__ Wvs,
    const float* __restrict__ Wsv, const float* __restrict__ Wvv,
    const float* __restrict__ Wf1, const float* __restrict__ bf1,
    const float* __restrict__ Wf2, const float* __restrict__ bf2,
    const float* __restrict__ Wf3, const float* __restrict__ bf3,
    const float* __restrict__ Wpost0, const float* __restrict__ bpost0,
    const float* __restrict__ Wpost1,
    float* __restrict__ out) {
  __shared__ float sinL[384][ET];   // [nsf_i | nsf_j | s]
  __shared__ float vinL[576][ET];   // rows K*3+m: [nvf_i | nvf_j | v]
  __shared__ float esL[128][ET];    // raw es; reused as zsL after gating
  __shared__ float evL[192][ET];    // raw ev; reused as zvL after gating
  __shared__ float elenL[128][ET];
  __shared__ float shL[4][ET];
  __shared__ float svhL[192][ET];   // sum_m v_in[K,m]*sh1[m]
  __shared__ float outsL[192][ET];
  __shared__ float outvL[192][ET];
  __shared__ float t1L[64][ET];     // s_in @ Wsv
  __shared__ float h1L[64][ET];
  __shared__ float h2L[64][ET];
  __shared__ float wL[192][ET];
  __shared__ int iL[ET], jL[ET];

  const int t = threadIdx.x;
  const int e0 = blockIdx.x * ET;

  if (t < ET) { iL[t] = eidx[e0 + t]; jL[t] = eidx[E_TOT + e0 + t]; }
  __syncthreads();

  // P0: loads
  for (int o = t; o < ET * DIM; o += 512) {
    int e = o / DIM, c = o % DIM;
    float x = edge_fea[(size_t)(e0 + e) * DIM + c];
    if (c < NS) esL[c][e] = x; else evL[c - NS][e] = x;
  }
  for (int o = t; o < 2 * ET * DIM; o += 512) {
    int p = o / DIM, c = o % DIM;
    int e = p >> 1, wh = p & 1;
    int node = wh ? jL[e] : iL[e];
    float x = node_fea[(size_t)node * DIM + c];
    if (c < NS) sinL[wh * NS + c][e] = x; else vinL[wh * 192 + (c - NS)][e] = x;
  }
  for (int o = t; o < ET * 128; o += 512) {
    int e = o >> 7, c = o & 127;
    elenL[c][e] = elen[(size_t)(e0 + e) * 128 + c];
  }
  if (t < ET * 4) { int e = t >> 2, m = t & 3; shL[m][e] = edge_sh[(size_t)(e0 + e) * 4 + m]; }
  __syncthreads();

  // P1: s = es@Wpre0/sqrt(128)+b ;  v = ev@Wpre1/8
  {
    const int u = t & 127, eh = t >> 7;  // 4 edges
    float a[4] = {0, 0, 0, 0};
    for (int k = 0; k < 128; ++k) {
      float w = Wpre0[k * 128 + u];
      const float4 x = *(const float4*)&esL[k][eh * 4];
      a[0] += x.x * w; a[1] += x.y * w; a[2] += x.z * w; a[3] += x.w * w;
    }
    float b = bpre0[u];
    #pragma unroll
    for (int q = 0; q < 4; ++q) sinL[256 + u][eh * 4 + q] = a[q] * INV_SQRT128 + b;
  }
  if (t < 384) {
    const int row = t % 192, eh = t / 192;  // 8 edges
    const int u = row / 3, m = row % 3;
    float a[8] = {0, 0, 0, 0, 0, 0, 0, 0};
    for (int k = 0; k < 64; ++k) {
      float w = Wpre1[k * 64 + u];
      const float4 x0 = *(const float4*)&evL[k * 3 + m][eh * 8];
      const float4 x1 = *(const float4*)&evL[k * 3 + m][eh * 8 + 4];
      a[0] += x0.x * w; a[1] += x0.y * w; a[2] += x0.z * w; a[3] += x0.w * w;
      a[4] += x1.x * w; a[5] += x1.y * w; a[6] += x1.z * w; a[7] += x1.w * w;
    }
    #pragma unroll
    for (int q = 0; q < 8; ++q) vinL[384 + row][eh * 8 + q] = a[q] * INV_8;
  }
  __syncthreads();

  // P2: svh[K][e] = sum_m v_in[K,m]*sh1[m]
  for (int o = t; o < 192 * ET; o += 512) {
    int e = o & 15, K = o >> 4;
    svhL[K][e] = vinL[K * 3 + 0][e] * shL[1][e] + vinL[K * 3 + 1][e] * shL[2][e] +
                 vinL[K * 3 + 2][e] * shL[3][e];
  }
  __syncthreads();

  // P3: out_s (t<384) || t1 = s_in@Wsv (t>=384)
  if (t < 384) {
    const int n = t % 192, eh = t / 192;  // 8 edges
    float a[8] = {0, 0, 0, 0, 0, 0, 0, 0};
    float b[8] = {0, 0, 0, 0, 0, 0, 0, 0};
    for (int k = 0; k < 384; ++k) {
      float w = Wss[k * 192 + n];
      const float4 x0 = *(const float4*)&sinL[k][eh * 8];
      const float4 x1 = *(const float4*)&sinL[k][eh * 8 + 4];
      a[0] += x0.x * w; a[1] += x0.y * w; a[2] += x0.z * w; a[3] += x0.w * w;
      a[4] += x1.x * w; a[5] += x1.y * w; a[6] += x1.z * w; a[7] += x1.w * w;
    }
    for (int k = 0; k < 192; ++k) {
      float w = Wvs[k * 192 + n];
      const float4 x0 = *(const float4*)&svhL[k][eh * 8];
      const float4 x1 = *(const float4*)&svhL[k][eh * 8 + 4];
      b[0] += x0.x * w; b[1] += x0.y * w; b[2] += x0.z * w; b[3] += x0.w * w;
      b[4] += x1.x * w; b[5] += x1.y * w; b[6] += x1.z * w; b[7] += x1.w * w;
    }
    #pragma unroll
    for (int q = 0; q < 8; ++q) {
      int e = eh * 8 + q;
      outsL[n][e] = (shL[0][e] * a[q] * INV_S384 + b[q] * INV_24) * RSQRT2;
    }
  } else {
    const int tt = t - 384;
    const int u = tt & 63, eh = tt >> 6;  // 8 edges
    float a[8] = {0, 0, 0, 0, 0, 0, 0, 0};
    for (int k = 0; k < 384; ++k) {
      float w = Wsv[k * 64 + u];
      const float4 x0 = *(const float4*)&sinL[k][eh * 8];
      const float4 x1 = *(const float4*)&sinL[k][eh * 8 + 4];
      a[0] += x0.x * w; a[1] += x0.y * w; a[2] += x0.z * w; a[3] += x0.w * w;
      a[4] += x1.x * w; a[5] += x1.y * w; a[6] += x1.z * w; a[7] += x1.w * w;
    }
    #pragma unroll
    for (int q = 0; q < 8; ++q) t1L[u][eh * 8 + q] = a[q];
  }
  __syncthreads();

  // P4: out_v (t<384) || h1 (t>=384)
  if (t < 384) {
    const int row = t % 192, eh = t / 192;  // 8 edges
    const int u = row / 3, m = row % 3;
    float a[8] = {0, 0, 0, 0, 0, 0, 0, 0};
    for (int K = 0; K < 192; ++K) {
      float w = Wvv[K * 64 + u];
      const float4 x0 = *(const float4*)&vinL[K * 3 + m][eh * 8];
      const float4 x1 = *(const float4*)&vinL[K * 3 + m][eh * 8 + 4];
      a[0] += x0.x * w; a[1] += x0.y * w; a[2] += x0.z * w; a[3] += x0.w * w;
      a[4] += x1.x * w; a[5] += x1.y * w; a[6] += x1.z * w; a[7] += x1.w * w;
    }
    #pragma unroll
    for (int q = 0; q < 8; ++q) {
      int e = eh * 8 + q;
      outvL[row][e] = (t1L[u][e] * shL[1 + m][e] * INV_S384 + shL[0][e] * a[q] * INV_S192) * RSQRT2;
    }
  } else {
    const int tt = t - 384;
    const int u = tt & 63, eh = tt >> 6;  // 8 edges
    float a[8] = {0, 0, 0, 0, 0, 0, 0, 0};
    for (int k = 0; k < 128; ++k) {
      float w = Wf1[k * 64 + u];
      const float4 x0 = *(const float4*)&elenL[k][eh * 8];
      const float4 x1 = *(const float4*)&elenL[k][eh * 8 + 4];
      a[0] += x0.x * w; a[1] += x0.y * w; a[2] += x0.z * w; a[3] += x0.w * w;
      a[4] += x1.x * w; a[5] += x1.y * w; a[6] += x1.z * w; a[7] += x1.w * w;
    }
    float b = bf1[u];
    #pragma unroll
    for (int q = 0; q < 8; ++q) h1L[u][eh * 8 + q] = siluf_(a[q] + b);
  }
  __syncthreads();

  // P5: h2 (all threads, 2 edges each)
  {
    const int u = t & 63, eh = t >> 6;
    float a0 = 0, a1 = 0;
    for (int k = 0; k < 64; ++k) {
      float w = Wf2[k * 64 + u];
      const float2 x = *(const float2*)&h1L[k][eh * 2];
      a0 += x.x * w; a1 += x.y * w;
    }
    float b = bf2[u];
    h2L[u][eh * 2 + 0] = siluf_(a0 + b);
    h2L[u][eh * 2 + 1] = siluf_(a1 + b);
  }
  __syncthreads();

  // P6: w = h2@Wf3 + bf3
  if (t < 384) {
    const int n = t % 192, eh = t / 192;  // 8 edges
    float a[8] = {0, 0, 0, 0, 0, 0, 0, 0};
    for (int k = 0; k < 64; ++k) {
      float w = Wf3[k * 192 + n];
      const float4 x0 = *(const float4*)&h2L[k][eh * 8];
      const float4 x1 = *(const float4*)&h2L[k][eh * 8 + 4];
      a[0] += x0.x * w; a[1] += x0.y * w; a[2] += x0.z * w; a[3] += x0.w * w;
      a[4] += x1.x * w; a[5] += x1.y * w; a[6] += x1.z * w; a[7] += x1.w * w;
    }
    float b = bf3[n];
    #pragma unroll
    for (int q = 0; q < 8; ++q) wL[n][eh * 8 + q] = a[q] + b;
  }
  __syncthreads();

  // P7: gating -> zs (esL), zv (evL)
  for (int o = t; o < 128 * ET; o += 512) {
    int e = o & 15, u = o >> 4;
    esL[u][e] = siluf_(outsL[u][e]) * wL[u][e];
  }
  for (int o = t; o < 192 * ET; o += 512) {
    int e = o & 15, row = o >> 4;
    int u = row / 3;
    evL[row][e] = outvL[row][e] * sigmoidf_(outsL[128 + u][e]) * wL[128 + u][e];
  }
  __syncthreads();

  // P8: post linears + add sc (in d_out)
  {
    const int u = t & 127, eh = t >> 7;  // 4 edges
    float a[4] = {0, 0, 0, 0};
    for (int k = 0; k < 128; ++k) {
      float w = Wpost0[k * 128 + u];
      const float4 x = *(const float4*)&esL[k][eh * 4];
      a[0] += x.x * w; a[1] += x.y * w; a[2] += x.z * w; a[3] += x.w * w;
    }
    float b = bpost0[u];
    #pragma unroll
    for (int q = 0; q < 4; ++q) {
      size_t o = (size_t)(e0 + eh * 4 + q) * DIM + u;
      out[o] = a[q] * INV_SQRT128 + b + out[o];
    }
  }
  if (t < 384) {
    const int row = t % 192, eh = t / 192;  // 8 edges
    const int u = row / 3, m = row % 3;
    float a[8] = {0, 0, 0, 0, 0, 0, 0, 0};
    for (int k = 0; k < 64; ++k) {
      float w = Wpost1[k * 64 + u];
      const float4 x0 = *(const float4*)&evL[k * 3 + m][eh * 8];
      const float4 x1 = *(const float4*)&evL[k * 3 + m][eh * 8 + 4];
      a[0] += x0.x * w; a[1] += x0.y * w; a[2] += x0.z * w; a[3] += x0.w * w;
      a[4] += x1.x * w; a[5] += x1.y * w; a[6] += x1.z * w; a[7] += x1.w * w;
    }
    #pragma unroll
    for (int q = 0; q < 8; ++q) {
      size_t o = (size_t)(e0 + eh * 8 + q) * DIM + NS + row;
      out[o] = a[q] * INV_8 + out[o];
    }
  }
}

// ---------------- K3: group statistics ----------------
__global__ __launch_bounds__(256) void k_stats(
    const float* __restrict__ out, const int* __restrict__ eidx,
    const int* __restrict__ batch, float* __restrict__ stats) {
  __shared__ float gacc[16][4];
  const int t = threadIdx.x;
  if (t < 64) ((float*)gacc)[t] = 0.0f;
  __syncthreads();
  const int el = t >> 4, l = t & 15;
  for (int ebase = blockIdx.x * 16; ebase < E_TOT; ebase += gridDim.x * 16) {
    int e = ebase + el;  // E_TOT divisible by 16 -> always valid
    const float* z = out + (size_t)e * DIM;
    float s1 = 0, s2 = 0, s2v = 0;
    for (int c = l; c < NS; c += 16) { float x = z[c]; s1 += x; s2 += x * x; }
    for (int c = NS + l; c < DIM; c += 16) { float x = z[c]; s2v += x * x; }
    #pragma unroll
    for (int msk = 8; msk; msk >>= 1) {
      s1 += __shfl_xor(s1, msk);
      s2 += __shfl_xor(s2, msk);
      s2v += __shfl_xor(s2v, msk);
    }
    if (l == 0) {
      int g = batch[eidx[e]];
      atomicAdd(&gacc[g][0], 1.0f);
      atomicAdd(&gacc[g][1], s1);
      atomicAdd(&gacc[g][2], s2);
      atomicAdd(&gacc[g][3], s2v);
    }
  }
  __syncthreads();
  if (t < 64) {
    float v = gacc[t >> 2][t & 3];
    if (v != 0.0f) atomicAdd(&stats[(t >> 2) * 16 + (t & 3)], v);
  }
}

// ---------------- K4: normalize + residual ----------------
__global__ __launch_bounds__(256) void k_norm(
    const float* __restrict__ edge_fea, const int* __restrict__ eidx,
    const int* __restrict__ batch, const float* __restrict__ stats,
    const float* __restrict__ gamma_s, const float* __restrict__ beta_s,
    const float* __restrict__ gamma_v, float* __restrict__ out) {
  __shared__ float meanL[16], invsL[16], invvL[16];
  __shared__ int gL[ET];
  const int t = threadIdx.x;
  const int e0 = blockIdx.x * ET;
  if (t < 16) {
    float cnt = fmaxf(stats[t * 16 + 0], 1.0f);
    float m = stats[t * 16 + 1] / (cnt * 128.0f);
    float var = stats[t * 16 + 2] / (cnt * 128.0f) - m * m;
    meanL[t] = m;
    invsL[t] = rsqrtf(var + 1e-5f);
    invvL[t] = rsqrtf(stats[t * 16 + 3] / (cnt * 192.0f) + 1e-5f);
  }
  if (t >= 32 && t < 32 + ET) gL[t - 32] = batch[eidx[e0 + t - 32]];
  __syncthreads();
  for (int o = t; o < ET * DIM; o += 256) {
    int e = o / DIM, c = o % DIM;
    int g = gL[e];
    size_t idx = (size_t)(e0 + e) * DIM + c;
    float z = out[idx];
    float r;
    if (c < NS) r = (z - meanL[g]) * invsL[g] * gamma_s[c] + beta_s[c];
    else r = z * invvL[g] * gamma_v[(c - NS) / 3];
    out[idx] = r + edge_fea[idx];
  }
}

extern "C" void kernel_launch(void* const* d_in, const int* in_sizes, int n_in,
                              void* d_out, int out_size, void* d_ws, size_t ws_size,
                              hipStream_t stream) {
  const float* node_fea = (const float*)d_in[0];
  const float* edge_oh  = (const float*)d_in[1];
  const float* edge_sh  = (const float*)d_in[2];
  const float* edge_fea = (const float*)d_in[3];
  const float* elen     = (const float*)d_in[4];
  const int*   eidx     = (const int*)d_in[5];
  const int*   batch    = (const int*)d_in[6];
  const float* Wsc_s    = (const float*)d_in[7];
  const float* Wsc_v    = (const float*)d_in[8];
  const float* Wpre0    = (const float*)d_in[9];
  const float* bpre0    = (const float*)d_in[10];
  const float* Wpre1    = (const float*)d_in[11];
  const float* Wss      = (const float*)d_in[12];
  const float* Wvs      = (const float*)d_in[13];
  const float* Wsv      = (const float*)d_in[14];
  const float* Wvv      = (const float*)d_in[15];
  const float* Wf1      = (const float*)d_in[16];
  const float* bf1      = (const float*)d_in[17];
  const float* Wf2      = (const float*)d_in[18];
  const float* bf2      = (const float*)d_in[19];
  const float* Wf3      = (const float*)d_in[20];
  const float* bf3      = (const float*)d_in[21];
  const float* Wpost0   = (const float*)d_in[22];
  const float* bpost0   = (const float*)d_in[23];
  const float* Wpost1   = (const float*)d_in[24];
  const float* gamma_s  = (const float*)d_in[25];
  const float* beta_s   = (const float*)d_in[26];
  const float* gamma_v  = (const float*)d_in[27];
  float* out = (float*)d_out;
  float* stats = (float*)d_ws;

  const int nblk = E_TOT / ET;  // 6250

  hipMemsetAsync(stats, 0, 16 * 16 * sizeof(float), stream);
  k_sc<<<nblk, 256, 0, stream>>>(edge_fea, edge_oh, Wsc_s, Wsc_v, out);
  k_main<<<nblk, 512, 0, stream>>>(node_fea, edge_sh, edge_fea, elen, eidx,
                                   Wpre0, bpre0, Wpre1, Wss, Wvs, Wsv, Wvv,
                                   Wf1, bf1, Wf2, bf2, Wf3, bf3,
                                   Wpost0, bpost0, Wpost1, out);
  k_stats<<<512, 256, 0, stream>>>(out, eidx, batch, stats);
  k_norm<<<nblk, 256, 0, stream>>>(edge_fea, eidx, batch, stats,
                                   gamma_s, beta_s, gamma_v, out);
}

// Round 2
// 1975.616 us; speedup vs baseline: 2.5201x; 2.5201x over previous
//
#include <hip/hip_runtime.h>
#include <math.h>

typedef unsigned int u32;
typedef __attribute__((ext_vector_type(8))) short bf16x8;
typedef __attribute__((ext_vector_type(4))) float f32x4;

#define E_TOT 100000
#define ET 16
constexpr int NS = 128, NV = 64, DIM = 320;

constexpr float SC_S_SCALE = 0.022097086912079608f;  // 1/sqrt(128*16)
constexpr float SC_V_SCALE = 0.03125f;               // 1/32
constexpr float INV_SQRT128 = 0.08838834764831845f;
constexpr float INV_8 = 0.125f;
constexpr float INV_S384 = 0.05103103630798288f;     // 1/sqrt(384)
constexpr float INV_24 = 0.041666666666666664f;      // 1/sqrt(576)
constexpr float INV_S192 = 0.07216878364870323f;     // 1/sqrt(192)
constexpr float RSQRT2 = 0.7071067811865476f;

__device__ __forceinline__ float sigmoidf_(float x) { return 1.0f / (1.0f + __expf(-x)); }
__device__ __forceinline__ float siluf_(float x) { return x * sigmoidf_(x); }

__device__ __forceinline__ float bf2f(unsigned short h) {
  u32 u = ((u32)h) << 16;
  return __builtin_bit_cast(float, u);
}
__device__ __forceinline__ unsigned short f2bf(float f) {
  u32 u = __builtin_bit_cast(u32, f);
  return (unsigned short)((u + 0x7fffu + ((u >> 16) & 1u)) >> 16);
}
__device__ __forceinline__ void gl_lds16(const void* g, void* l) {
  __builtin_amdgcn_global_load_lds((const __attribute__((address_space(1))) u32*)g,
                                   (__attribute__((address_space(3))) u32*)l, 16, 0, 0);
}

// ---------------- K0: weight prep (f32 -> bf16, transposed to [u][k=(s,v)]) ----------------
__global__ __launch_bounds__(256) void k_prep(const float* __restrict__ Ws,
                                              const float* __restrict__ Wv,
                                              unsigned short* __restrict__ W2s,
                                              unsigned short* __restrict__ Btv) {
  int o = blockIdx.x * 256 + threadIdx.x;
  if (o < 128 * 2048) {
    int u = o >> 11, k = o & 2047, s = k >> 7, v = k & 127;
    W2s[o] = f2bf(Ws[((size_t)(v * 16 + s)) * 128 + u]);
  } else {
    int o2 = o - 128 * 2048;
    if (o2 < 64 * 1024) {
      int u = o2 >> 10, k = o2 & 1023, s = k >> 6, v = k & 63;
      Btv[o2] = f2bf(Wv[((size_t)(v * 16 + s)) * 64 + u]);
    }
  }
}

// ---------------- K1a: sc_s via MFMA. M=64 edges, N=128, K=2048 (16 s-chunks of 128) ----
#define MEs 64
__global__ __launch_bounds__(256, 2) void k_sc_s(
    const float* __restrict__ edge_fea, const float* __restrict__ ohp,
    const unsigned short* __restrict__ W2s,  // [128 u][2048 k] bf16
    float* __restrict__ out) {
  __shared__ unsigned short esB[64][136];      // raw es bf16, padded rows
  __shared__ float ohL[64][16];
  __shared__ unsigned short Abuf[64 * 128];    // swizzled A chunk, row 256B
  __shared__ unsigned short Bbuf[128 * 128];   // swizzled B chunk, row 256B
  const int t = threadIdx.x;
  const int lane = t & 63, ww = t >> 6;
  const int e0 = blockIdx.x * MEs;
  const int nE = min(MEs, E_TOT - e0);

  for (int o = t; o < 64 * 32; o += 256) {
    int e = o >> 5, c4 = (o & 31) << 2;
    float4 x = (e < nE) ? *(const float4*)&edge_fea[(size_t)(e0 + e) * DIM + c4]
                        : make_float4(0.f, 0.f, 0.f, 0.f);
    esB[e][c4 + 0] = f2bf(x.x); esB[e][c4 + 1] = f2bf(x.y);
    esB[e][c4 + 2] = f2bf(x.z); esB[e][c4 + 3] = f2bf(x.w);
  }
  for (int o = t; o < 64 * 16; o += 256) {
    int e = o >> 4, s = o & 15;
    ohL[e][s] = (e < nE) ? ohp[(size_t)(e0 + e) * 16 + s] : 0.f;
  }
  __syncthreads();

  f32x4 acc[4][2];
  #pragma unroll
  for (int a = 0; a < 4; ++a)
    #pragma unroll
    for (int b = 0; b < 2; ++b) acc[a][b] = (f32x4){0.f, 0.f, 0.f, 0.f};

  for (int s = 0; s < 16; ++s) {
    // stage B chunk [128u][128k] via global_load_lds, source pre-swizzled
    {
      const char* sb = (const char*)W2s + s * 256;
      #pragma unroll
      for (int it = 0; it < 8; ++it) {
        int n = it * 256 + t;
        int u = n >> 4, gp = n & 15, g = gp ^ (u & 7);
        gl_lds16(sb + (size_t)u * 4096 + g * 16, (char*)Bbuf + n * 16);
      }
    }
    // build A chunk: A[e][v] = es[e][v] * oh[e][s], swizzled store
    #pragma unroll
    for (int it = 0; it < 4; ++it) {
      int n = it * 256 + t;
      int e = n >> 4, gp = n & 15, g = gp ^ (e & 7);
      float ohs = ohL[e][s];
      union { uint4 q; unsigned short h[8]; } in, ov;
      in.q = *(const uint4*)&esB[e][g * 8];
      #pragma unroll
      for (int j = 0; j < 8; ++j) ov.h[j] = f2bf(bf2f(in.h[j]) * ohs);
      *(uint4*)((char*)Abuf + e * 256 + gp * 16) = ov.q;
    }
    __syncthreads();

    const int cb = (lane >> 4) << 4;
    #pragma unroll
    for (int ks = 0; ks < 4; ++ks) {
      int cbyte = ks * 64 + cb;
      bf16x8 bfr[2], afr[4];
      #pragma unroll
      for (int ct = 0; ct < 2; ++ct) {
        int u = ww * 32 + ct * 16 + (lane & 15);
        bfr[ct] = *(const bf16x8*)((const char*)Bbuf + u * 256 + (cbyte ^ ((u & 7) << 4)));
      }
      #pragma unroll
      for (int rt = 0; rt < 4; ++rt) {
        int e = rt * 16 + (lane & 15);
        afr[rt] = *(const bf16x8*)((const char*)Abuf + e * 256 + (cbyte ^ ((e & 7) << 4)));
      }
      #pragma unroll
      for (int rt = 0; rt < 4; ++rt)
        #pragma unroll
        for (int ct = 0; ct < 2; ++ct)
          acc[rt][ct] = __builtin_amdgcn_mfma_f32_16x16x32_bf16(afr[rt], bfr[ct], acc[rt][ct], 0, 0, 0);
    }
    __syncthreads();
  }

  #pragma unroll
  for (int rt = 0; rt < 4; ++rt) {
    int ebase = rt * 16 + ((lane >> 4) << 2);
    #pragma unroll
    for (int ct = 0; ct < 2; ++ct) {
      int u = ww * 32 + ct * 16 + (lane & 15);
      #pragma unroll
      for (int j = 0; j < 4; ++j) {
        int ee = ebase + j;
        if (ee < nE) out[(size_t)(e0 + ee) * DIM + u] = acc[rt][ct][j] * SC_S_SCALE;
      }
    }
  }
}

// ---------------- K1b: sc_v via MFMA. M=192 rows (e,m), N=64, K=1024 (16 s-chunks of 64) ----
__global__ __launch_bounds__(256, 2) void k_sc_v(
    const float* __restrict__ edge_fea, const float* __restrict__ ohp,
    const unsigned short* __restrict__ Btv,  // [64 u][1024 k] bf16
    float* __restrict__ out) {
  __shared__ unsigned short evT[3][64][72];    // [m][e][v], padded rows
  __shared__ float ohL[64][16];
  __shared__ unsigned short Abuf[192 * 64];    // swizzled, row 128B
  __shared__ unsigned short Bbuf[64 * 64];     // swizzled, row 128B
  const int t = threadIdx.x;
  const int lane = t & 63, ww = t >> 6;
  const int e0 = blockIdx.x * MEs;
  const int nE = min(MEs, E_TOT - e0);

  for (int o = t; o < 64 * 192; o += 256) {
    int e = o / 192, c = o % 192;
    int v = c / 3, m = c % 3;
    float x = (e < nE) ? edge_fea[(size_t)(e0 + e) * DIM + NS + c] : 0.f;
    evT[m][e][v] = f2bf(x);
  }
  for (int o = t; o < 64 * 16; o += 256) {
    int e = o >> 4, s = o & 15;
    ohL[e][s] = (e < nE) ? ohp[(size_t)(e0 + e) * 16 + s] : 0.f;
  }
  __syncthreads();

  f32x4 acc[12];
  #pragma unroll
  for (int a = 0; a < 12; ++a) acc[a] = (f32x4){0.f, 0.f, 0.f, 0.f};

  for (int s = 0; s < 16; ++s) {
    #pragma unroll
    for (int it = 0; it < 2; ++it) {
      int n = it * 256 + t;
      int u = n >> 3, gp = n & 7, g = gp ^ (u & 7);
      gl_lds16((const char*)Btv + (size_t)u * 2048 + s * 128 + g * 16, (char*)Bbuf + n * 16);
    }
    #pragma unroll
    for (int it = 0; it < 6; ++it) {
      int n = it * 256 + t;
      int r = n >> 3, gp = n & 7, g = gp ^ (r & 7);
      int e = r / 3, m = r - e * 3;
      float ohs = ohL[e][s];
      union { uint4 q; unsigned short h[8]; } in, ov;
      in.q = *(const uint4*)&evT[m][e][g * 8];
      #pragma unroll
      for (int j = 0; j < 8; ++j) ov.h[j] = f2bf(bf2f(in.h[j]) * ohs);
      *(uint4*)((char*)Abuf + r * 128 + gp * 16) = ov.q;
    }
    __syncthreads();

    const int cb = (lane >> 4) << 4;
    #pragma unroll
    for (int ks = 0; ks < 2; ++ks) {
      int cbyte = ks * 64 + cb;
      int u = ww * 16 + (lane & 15);
      bf16x8 bfr = *(const bf16x8*)((const char*)Bbuf + u * 128 + (cbyte ^ ((u & 7) << 4)));
      #pragma unroll
      for (int rt = 0; rt < 12; ++rt) {
        int r = rt * 16 + (lane & 15);
        bf16x8 afr = *(const bf16x8*)((const char*)Abuf + r * 128 + (cbyte ^ ((r & 7) << 4)));
        acc[rt] = __builtin_amdgcn_mfma_f32_16x16x32_bf16(afr, bfr, acc[rt], 0, 0, 0);
      }
    }
    __syncthreads();
  }

  #pragma unroll
  for (int rt = 0; rt < 12; ++rt) {
    int rbase = rt * 16 + ((lane >> 4) << 2);
    int u = ww * 16 + (lane & 15);
    #pragma unroll
    for (int j = 0; j < 4; ++j) {
      int r = rbase + j;
      int e = r / 3, m = r - e * 3;
      if (e < nE) out[(size_t)(e0 + e) * DIM + NS + u * 3 + m] = acc[rt][j] * SC_V_SCALE;
    }
  }
}

// ---------------- K2: fused main chain, accumulates onto sc in d_out ----------------
__global__ __launch_bounds__(512, 1) void k_main(
    const float* __restrict__ node_fea, const float* __restrict__ edge_sh,
    const float* __restrict__ edge_fea, const float* __restrict__ elen,
    const int* __restrict__ eidx,
    const float* __restrict__ Wpre0, const float* __restrict__ bpre0,
    const float* __restrict__ Wpre1,
    const float* __restrict__ Wss, const float* __restrict__ Wvs,
    const float* __restrict__ Wsv, const float* __restrict__ Wvv,
    const float* __restrict__ Wf1, const float* __restrict__ bf1,
    const float* __restrict__ Wf2, const float* __restrict__ bf2,
    const float* __restrict__ Wf3, const float* __restrict__ bf3,
    const float* __restrict__ Wpost0, const float* __restrict__ bpost0,
    const float* __restrict__ Wpost1,
    float* __restrict__ out) {
  __shared__ float sinL[384][ET];   // [nsf_i | nsf_j | s]
  __shared__ float vinL[576][ET];   // rows K*3+m: [nvf_i | nvf_j | v]
  __shared__ float esL[128][ET];    // raw es; reused as zsL after gating
  __shared__ float evL[192][ET];    // raw ev; reused as zvL after gating
  __shared__ float elenL[128][ET];
  __shared__ float shL[4][ET];
  __shared__ float svhL[192][ET];   // sum_m v_in[K,m]*sh1[m]
  __shared__ float outsL[192][ET];
  __shared__ float outvL[192][ET];
  __shared__ float t1L[64][ET];     // s_in @ Wsv
  __shared__ float h1L[64][ET];
  __shared__ float h2L[64][ET];
  __shared__ float wL[192][ET];
  __shared__ int iL[ET], jL[ET];

  const int t = threadIdx.x;
  const int e0 = blockIdx.x * ET;

  if (t < ET) { iL[t] = eidx[e0 + t]; jL[t] = eidx[E_TOT + e0 + t]; }
  __syncthreads();

  for (int o = t; o < ET * DIM; o += 512) {
    int e = o / DIM, c = o % DIM;
    float x = edge_fea[(size_t)(e0 + e) * DIM + c];
    if (c < NS) esL[c][e] = x; else evL[c - NS][e] = x;
  }
  for (int o = t; o < 2 * ET * DIM; o += 512) {
    int p = o / DIM, c = o % DIM;
    int e = p >> 1, wh = p & 1;
    int node = wh ? jL[e] : iL[e];
    float x = node_fea[(size_t)node * DIM + c];
    if (c < NS) sinL[wh * NS + c][e] = x; else vinL[wh * 192 + (c - NS)][e] = x;
  }
  for (int o = t; o < ET * 128; o += 512) {
    int e = o >> 7, c = o & 127;
    elenL[c][e] = elen[(size_t)(e0 + e) * 128 + c];
  }
  if (t < ET * 4) { int e = t >> 2, m = t & 3; shL[m][e] = edge_sh[(size_t)(e0 + e) * 4 + m]; }
  __syncthreads();

  {
    const int u = t & 127, eh = t >> 7;
    float a[4] = {0, 0, 0, 0};
    for (int k = 0; k < 128; ++k) {
      float w = Wpre0[k * 128 + u];
      const float4 x = *(const float4*)&esL[k][eh * 4];
      a[0] += x.x * w; a[1] += x.y * w; a[2] += x.z * w; a[3] += x.w * w;
    }
    float b = bpre0[u];
    #pragma unroll
    for (int q = 0; q < 4; ++q) sinL[256 + u][eh * 4 + q] = a[q] * INV_SQRT128 + b;
  }
  if (t < 384) {
    const int row = t % 192, eh = t / 192;
    const int u = row / 3, m = row % 3;
    float a[8] = {0, 0, 0, 0, 0, 0, 0, 0};
    for (int k = 0; k < 64; ++k) {
      float w = Wpre1[k * 64 + u];
      const float4 x0 = *(const float4*)&evL[k * 3 + m][eh * 8];
      const float4 x1 = *(const float4*)&evL[k * 3 + m][eh * 8 + 4];
      a[0] += x0.x * w; a[1] += x0.y * w; a[2] += x0.z * w; a[3] += x0.w * w;
      a[4] += x1.x * w; a[5] += x1.y * w; a[6] += x1.z * w; a[7] += x1.w * w;
    }
    #pragma unroll
    for (int q = 0; q < 8; ++q) vinL[384 + row][eh * 8 + q] = a[q] * INV_8;
  }
  __syncthreads();

  for (int o = t; o < 192 * ET; o += 512) {
    int e = o & 15, K = o >> 4;
    svhL[K][e] = vinL[K * 3 + 0][e] * shL[1][e] + vinL[K * 3 + 1][e] * shL[2][e] +
                 vinL[K * 3 + 2][e] * shL[3][e];
  }
  __syncthreads();

  if (t < 384) {
    const int n = t % 192, eh = t / 192;
    float a[8] = {0, 0, 0, 0, 0, 0, 0, 0};
    float b[8] = {0, 0, 0, 0, 0, 0, 0, 0};
    for (int k = 0; k < 384; ++k) {
      float w = Wss[k * 192 + n];
      const float4 x0 = *(const float4*)&sinL[k][eh * 8];
      const float4 x1 = *(const float4*)&sinL[k][eh * 8 + 4];
      a[0] += x0.x * w; a[1] += x0.y * w; a[2] += x0.z * w; a[3] += x0.w * w;
      a[4] += x1.x * w; a[5] += x1.y * w; a[6] += x1.z * w; a[7] += x1.w * w;
    }
    for (int k = 0; k < 192; ++k) {
      float w = Wvs[k * 192 + n];
      const float4 x0 = *(const float4*)&svhL[k][eh * 8];
      const float4 x1 = *(const float4*)&svhL[k][eh * 8 + 4];
      b[0] += x0.x * w; b[1] += x0.y * w; b[2] += x0.z * w; b[3] += x0.w * w;
      b[4] += x1.x * w; b[5] += x1.y * w; b[6] += x1.z * w; b[7] += x1.w * w;
    }
    #pragma unroll
    for (int q = 0; q < 8; ++q) {
      int e = eh * 8 + q;
      outsL[n][e] = (shL[0][e] * a[q] * INV_S384 + b[q] * INV_24) * RSQRT2;
    }
  } else {
    const int tt = t - 384;
    const int u = tt & 63, eh = tt >> 6;
    float a[8] = {0, 0, 0, 0, 0, 0, 0, 0};
    for (int k = 0; k < 384; ++k) {
      float w = Wsv[k * 64 + u];
      const float4 x0 = *(const float4*)&sinL[k][eh * 8];
      const float4 x1 = *(const float4*)&sinL[k][eh * 8 + 4];
      a[0] += x0.x * w; a[1] += x0.y * w; a[2] += x0.z * w; a[3] += x0.w * w;
      a[4] += x1.x * w; a[5] += x1.y * w; a[6] += x1.z * w; a[7] += x1.w * w;
    }
    #pragma unroll
    for (int q = 0; q < 8; ++q) t1L[u][eh * 8 + q] = a[q];
  }
  __syncthreads();

  if (t < 384) {
    const int row = t % 192, eh = t / 192;
    const int u = row / 3, m = row % 3;
    float a[8] = {0, 0, 0, 0, 0, 0, 0, 0};
    for (int K = 0; K < 192; ++K) {
      float w = Wvv[K * 64 + u];
      const float4 x0 = *(const float4*)&vinL[K * 3 + m][eh * 8];
      const float4 x1 = *(const float4*)&vinL[K * 3 + m][eh * 8 + 4];
      a[0] += x0.x * w; a[1] += x0.y * w; a[2] += x0.z * w; a[3] += x0.w * w;
      a[4] += x1.x * w; a[5] += x1.y * w; a[6] += x1.z * w; a[7] += x1.w * w;
    }
    #pragma unroll
    for (int q = 0; q < 8; ++q) {
      int e = eh * 8 + q;
      outvL[row][e] = (t1L[u][e] * shL[1 + m][e] * INV_S384 + shL[0][e] * a[q] * INV_S192) * RSQRT2;
    }
  } else {
    const int tt = t - 384;
    const int u = tt & 63, eh = tt >> 6;
    float a[8] = {0, 0, 0, 0, 0, 0, 0, 0};
    for (int k = 0; k < 128; ++k) {
      float w = Wf1[k * 64 + u];
      const float4 x0 = *(const float4*)&elenL[k][eh * 8];
      const float4 x1 = *(const float4*)&elenL[k][eh * 8 + 4];
      a[0] += x0.x * w; a[1] += x0.y * w; a[2] += x0.z * w; a[3] += x0.w * w;
      a[4] += x1.x * w; a[5] += x1.y * w; a[6] += x1.z * w; a[7] += x1.w * w;
    }
    float b = bf1[u];
    #pragma unroll
    for (int q = 0; q < 8; ++q) h1L[u][eh * 8 + q] = siluf_(a[q] + b);
  }
  __syncthreads();

  {
    const int u = t & 63, eh = t >> 6;
    float a0 = 0, a1 = 0;
    for (int k = 0; k < 64; ++k) {
      float w = Wf2[k * 64 + u];
      const float2 x = *(const float2*)&h1L[k][eh * 2];
      a0 += x.x * w; a1 += x.y * w;
    }
    float b = bf2[u];
    h2L[u][eh * 2 + 0] = siluf_(a0 + b);
    h2L[u][eh * 2 + 1] = siluf_(a1 + b);
  }
  __syncthreads();

  if (t < 384) {
    const int n = t % 192, eh = t / 192;
    float a[8] = {0, 0, 0, 0, 0, 0, 0, 0};
    for (int k = 0; k < 64; ++k) {
      float w = Wf3[k * 192 + n];
      const float4 x0 = *(const float4*)&h2L[k][eh * 8];
      const float4 x1 = *(const float4*)&h2L[k][eh * 8 + 4];
      a[0] += x0.x * w; a[1] += x0.y * w; a[2] += x0.z * w; a[3] += x0.w * w;
      a[4] += x1.x * w; a[5] += x1.y * w; a[6] += x1.z * w; a[7] += x1.w * w;
    }
    float b = bf3[n];
    #pragma unroll
    for (int q = 0; q < 8; ++q) wL[n][eh * 8 + q] = a[q] + b;
  }
  __syncthreads();

  for (int o = t; o < 128 * ET; o += 512) {
    int e = o & 15, u = o >> 4;
    esL[u][e] = siluf_(outsL[u][e]) * wL[u][e];
  }
  for (int o = t; o < 192 * ET; o += 512) {
    int e = o & 15, row = o >> 4;
    int u = row / 3;
    evL[row][e] = outvL[row][e] * sigmoidf_(outsL[128 + u][e]) * wL[128 + u][e];
  }
  __syncthreads();

  {
    const int u = t & 127, eh = t >> 7;
    float a[4] = {0, 0, 0, 0};
    for (int k = 0; k < 128; ++k) {
      float w = Wpost0[k * 128 + u];
      const float4 x = *(const float4*)&esL[k][eh * 4];
      a[0] += x.x * w; a[1] += x.y * w; a[2] += x.z * w; a[3] += x.w * w;
    }
    float b = bpost0[u];
    #pragma unroll
    for (int q = 0; q < 4; ++q) {
      size_t o = (size_t)(e0 + eh * 4 + q) * DIM + u;
      out[o] = a[q] * INV_SQRT128 + b + out[o];
    }
  }
  if (t < 384) {
    const int row = t % 192, eh = t / 192;
    const int u = row / 3, m = row % 3;
    float a[8] = {0, 0, 0, 0, 0, 0, 0, 0};
    for (int k = 0; k < 64; ++k) {
      float w = Wpost1[k * 64 + u];
      const float4 x0 = *(const float4*)&evL[k * 3 + m][eh * 8];
      const float4 x1 = *(const float4*)&evL[k * 3 + m][eh * 8 + 4];
      a[0] += x0.x * w; a[1] += x0.y * w; a[2] += x0.z * w; a[3] += x0.w * w;
      a[4] += x1.x * w; a[5] += x1.y * w; a[6] += x1.z * w; a[7] += x1.w * w;
    }
    #pragma unroll
    for (int q = 0; q < 8; ++q) {
      size_t o = (size_t)(e0 + eh * 8 + q) * DIM + NS + row;
      out[o] = a[q] * INV_8 + out[o];
    }
  }
}

// ---------------- K3: group statistics ----------------
__global__ __launch_bounds__(256) void k_stats(
    const float* __restrict__ out, const int* __restrict__ eidx,
    const int* __restrict__ batch, float* __restrict__ stats) {
  __shared__ float gacc[16][4];
  const int t = threadIdx.x;
  if (t < 64) ((float*)gacc)[t] = 0.0f;
  __syncthreads();
  const int el = t >> 4, l = t & 15;
  for (int ebase = blockIdx.x * 16; ebase < E_TOT; ebase += gridDim.x * 16) {
    int e = ebase + el;
    const float* z = out + (size_t)e * DIM;
    float s1 = 0, s2 = 0, s2v = 0;
    for (int c = l; c < NS; c += 16) { float x = z[c]; s1 += x; s2 += x * x; }
    for (int c = NS + l; c < DIM; c += 16) { float x = z[c]; s2v += x * x; }
    #pragma unroll
    for (int msk = 8; msk; msk >>= 1) {
      s1 += __shfl_xor(s1, msk);
      s2 += __shfl_xor(s2, msk);
      s2v += __shfl_xor(s2v, msk);
    }
    if (l == 0) {
      int g = batch[eidx[e]];
      atomicAdd(&gacc[g][0], 1.0f);
      atomicAdd(&gacc[g][1], s1);
      atomicAdd(&gacc[g][2], s2);
      atomicAdd(&gacc[g][3], s2v);
    }
  }
  __syncthreads();
  if (t < 64) {
    float v = gacc[t >> 2][t & 3];
    if (v != 0.0f) atomicAdd(&stats[(t >> 2) * 16 + (t & 3)], v);
  }
}

// ---------------- K4: normalize + residual ----------------
__global__ __launch_bounds__(256) void k_norm(
    const float* __restrict__ edge_fea, const int* __restrict__ eidx,
    const int* __restrict__ batch, const float* __restrict__ stats,
    const float* __restrict__ gamma_s, const float* __restrict__ beta_s,
    const float* __restrict__ gamma_v, float* __restrict__ out) {
  __shared__ float meanL[16], invsL[16], invvL[16];
  __shared__ int gL[ET];
  const int t = threadIdx.x;
  const int e0 = blockIdx.x * ET;
  if (t < 16) {
    float cnt = fmaxf(stats[t * 16 + 0], 1.0f);
    float m = stats[t * 16 + 1] / (cnt * 128.0f);
    float var = stats[t * 16 + 2] / (cnt * 128.0f) - m * m;
    meanL[t] = m;
    invsL[t] = rsqrtf(var + 1e-5f);
    invvL[t] = rsqrtf(stats[t * 16 + 3] / (cnt * 192.0f) + 1e-5f);
  }
  if (t >= 32 && t < 32 + ET) gL[t - 32] = batch[eidx[e0 + t - 32]];
  __syncthreads();
  for (int o = t; o < ET * DIM; o += 256) {
    int e = o / DIM, c = o % DIM;
    int g = gL[e];
    size_t idx = (size_t)(e0 + e) * DIM + c;
    float z = out[idx];
    float r;
    if (c < NS) r = (z - meanL[g]) * invsL[g] * gamma_s[c] + beta_s[c];
    else r = z * invvL[g] * gamma_v[(c - NS) / 3];
    out[idx] = r + edge_fea[idx];
  }
}

extern "C" void kernel_launch(void* const* d_in, const int* in_sizes, int n_in,
                              void* d_out, int out_size, void* d_ws, size_t ws_size,
                              hipStream_t stream) {
  const float* node_fea = (const float*)d_in[0];
  const float* edge_oh  = (const float*)d_in[1];
  const float* edge_sh  = (const float*)d_in[2];
  const float* edge_fea = (const float*)d_in[3];
  const float* elen     = (const float*)d_in[4];
  const int*   eidx     = (const int*)d_in[5];
  const int*   batch    = (const int*)d_in[6];
  const float* Wsc_s    = (const float*)d_in[7];
  const float* Wsc_v    = (const float*)d_in[8];
  const float* Wpre0    = (const float*)d_in[9];
  const float* bpre0    = (const float*)d_in[10];
  const float* Wpre1    = (const float*)d_in[11];
  const float* Wss      = (const float*)d_in[12];
  const float* Wvs      = (const float*)d_in[13];
  const float* Wsv      = (const float*)d_in[14];
  const float* Wvv      = (const float*)d_in[15];
  const float* Wf1      = (const float*)d_in[16];
  const float* bf1      = (const float*)d_in[17];
  const float* Wf2      = (const float*)d_in[18];
  const float* bf2      = (const float*)d_in[19];
  const float* Wf3      = (const float*)d_in[20];
  const float* bf3      = (const float*)d_in[21];
  const float* Wpost0   = (const float*)d_in[22];
  const float* bpost0   = (const float*)d_in[23];
  const float* Wpost1   = (const float*)d_in[24];
  const float* gamma_s  = (const float*)d_in[25];
  const float* beta_s   = (const float*)d_in[26];
  const float* gamma_v  = (const float*)d_in[27];
  float* out = (float*)d_out;

  float* stats = (float*)d_ws;                                  // 1 KB
  unsigned short* W2s = (unsigned short*)((char*)d_ws + 1024);  // 512 KB
  unsigned short* Btv = W2s + 128 * 2048;                       // 128 KB

  const int nblk16 = E_TOT / ET;            // 6250
  const int nblk64 = (E_TOT + MEs - 1) / MEs;  // 1563

  hipMemsetAsync(stats, 0, 16 * 16 * sizeof(float), stream);
  k_prep<<<1280, 256, 0, stream>>>(Wsc_s, Wsc_v, W2s, Btv);
  k_sc_s<<<nblk64, 256, 0, stream>>>(edge_fea, edge_oh, W2s, out);
  k_sc_v<<<nblk64, 256, 0, stream>>>(edge_fea, edge_oh, Btv, out);
  k_main<<<nblk16, 512, 0, stream>>>(node_fea, edge_sh, edge_fea, elen, eidx,
                                     Wpre0, bpre0, Wpre1, Wss, Wvs, Wsv, Wvv,
                                     Wf1, bf1, Wf2, bf2, Wf3, bf3,
                                     Wpost0, bpost0, Wpost1, out);
  k_stats<<<512, 256, 0, stream>>>(out, eidx, batch, stats);
  k_norm<<<nblk16, 256, 0, stream>>>(edge_fea, eidx, batch, stats,
                                     gamma_s, beta_s, gamma_v, out);
}

// Round 3
// 1259.223 us; speedup vs baseline: 3.9539x; 1.5689x over previous
//
#include <hip/hip_runtime.h>
#include <math.h>

typedef unsigned int u32;
typedef unsigned short u16;
typedef __attribute__((ext_vector_type(8))) short bf16x8;
typedef __attribute__((ext_vector_type(4))) float f32x4;

#define E_TOT 100000
#define ET 16
constexpr int NS = 128, NV = 64, DIM = 320;

constexpr float SC_S_SCALE = 0.022097086912079608f;  // 1/sqrt(128*16)
constexpr float SC_V_SCALE = 0.03125f;               // 1/32
constexpr float INV_SQRT128 = 0.08838834764831845f;
constexpr float INV_8 = 0.125f;
constexpr float INV_S384 = 0.05103103630798288f;     // 1/sqrt(384)
constexpr float INV_24 = 0.041666666666666664f;      // 1/sqrt(576)
constexpr float INV_S192 = 0.07216878364870323f;     // 1/sqrt(192)
constexpr float RSQRT2 = 0.7071067811865476f;

__device__ __forceinline__ float sigmoidf_(float x) { return 1.0f / (1.0f + __expf(-x)); }
__device__ __forceinline__ float siluf_(float x) { return x * sigmoidf_(x); }

__device__ __forceinline__ float bf2f(u16 h) {
  u32 u = ((u32)h) << 16;
  return __builtin_bit_cast(float, u);
}
__device__ __forceinline__ u16 f2bf(float f) {
  u32 u = __builtin_bit_cast(u32, f);
  return (u16)((u + 0x7fffu + ((u >> 16) & 1u)) >> 16);
}
__device__ __forceinline__ void gl_lds16(const void* g, void* l) {
  __builtin_amdgcn_global_load_lds((const __attribute__((address_space(1))) u32*)g,
                                   (__attribute__((address_space(3))) u32*)l, 16, 0, 0);
}
// swizzled bf16 LDS store/load (XOR byte bits 4-6 with row&7) — rowB multiple of 128
__device__ __forceinline__ void stb(char* base, int row, int rowB, int colByte, u16 v) {
  *(u16*)(base + row * rowB + (colByte ^ ((row & 7) << 4))) = v;
}
__device__ __forceinline__ bf16x8 ldb8(const char* base, int row, int rowB, int colByte) {
  return *(const bf16x8*)(base + row * rowB + (colByte ^ ((row & 7) << 4)));
}

// ---------------- workspace layout (bytes) ----------------
// 0       : stats (1 KB)
// 1024    : bf16 weights, contiguous in prep order (1,081,344 B)
// 1082368 : outsG bf16 [E][192]
// 39482368: outvG bf16 [E][192] (cols m*64+u)
#define OFF_WBF   1024
#define OFF_OUTS  1082368
#define OFF_OUTV  39482368
#define WS_NEED   77882368
// cumulative element offsets within the bf16 weight block
#define C0 262144   /* W2s  (Wsc_s^T [128][2048]) */
#define C1 327680   /* Btv  (Wsc_v^T [64][1024]) */
#define C2 344064   /* Wpre0T [128][128] */
#define C3 348160   /* Wpre1T [64][64] */
#define C4 421888   /* WssT [192][384] */
#define C5 458752   /* WvsT [192][192] */
#define C6 483328   /* WsvT [64][384] */
#define C7 495616   /* WvvT [64][192] */
#define C8 503808   /* Wf1T [64][128] */
#define C9 507904   /* Wf2T [64][64] */
#define C10 520192  /* Wf3T [192][64] */
#define C11 536576  /* Wpost0T [128][128] */
#define C12 540672  /* Wpost1T [64][64] */

// ---------------- K0: weight prep ----------------
__global__ __launch_bounds__(256) void k_prep(
    const float* __restrict__ Wsc_s, const float* __restrict__ Wsc_v,
    const float* __restrict__ Wpre0, const float* __restrict__ Wpre1,
    const float* __restrict__ Wss, const float* __restrict__ Wvs,
    const float* __restrict__ Wsv, const float* __restrict__ Wvv,
    const float* __restrict__ Wf1, const float* __restrict__ Wf2,
    const float* __restrict__ Wf3, const float* __restrict__ Wpost0,
    const float* __restrict__ Wpost1, u16* __restrict__ dst, int nlim) {
  int o = blockIdx.x * 256 + threadIdx.x;
  if (o >= nlim) return;
  float v;
  if (o < C0) { int u=o>>11,k=o&2047,s=k>>7,vv=k&127; v = Wsc_s[((size_t)(vv*16+s))*128+u]; }
  else if (o < C1) { int oo=o-C0; int u=oo>>10,k=oo&1023,s=k>>6,vv=k&63; v = Wsc_v[((size_t)(vv*16+s))*64+u]; }
  else if (o < C2) { int oo=o-C1; int u=oo>>7,k=oo&127; v = Wpre0[k*128+u]*INV_SQRT128; }
  else if (o < C3) { int oo=o-C2; int u=oo>>6,k=oo&63; v = Wpre1[k*64+u]*INV_8; }
  else if (o < C4) { int oo=o-C3; int u=oo/384,k=oo%384; v = Wss[k*192+u]*(INV_S384*RSQRT2); }
  else if (o < C5) { int oo=o-C4; int u=oo/192,k=oo%192; v = Wvs[k*192+u]*(INV_24*RSQRT2); }
  else if (o < C6) { int oo=o-C5; int u=oo/384,k=oo%384; v = Wsv[k*64+u]*(INV_S384*RSQRT2); }
  else if (o < C7) { int oo=o-C6; int u=oo/192,k=oo%192; v = Wvv[k*64+u]*(INV_S192*RSQRT2); }
  else if (o < C8) { int oo=o-C7; int u=oo>>7,k=oo&127; v = Wf1[k*64+u]; }
  else if (o < C9) { int oo=o-C8; int u=oo>>6,k=oo&63; v = Wf2[k*64+u]; }
  else if (o < C10) { int oo=o-C9; int u=oo>>6,k=oo&63; v = Wf3[k*192+u]; }
  else if (o < C11) { int oo=o-C10; int u=oo>>7,k=oo&127; v = Wpost0[k*128+u]*INV_SQRT128; }
  else { int oo=o-C11; int u=oo>>6,k=oo&63; v = Wpost1[k*64+u]*INV_8; }
  dst[o] = f2bf(v);
}

// ---------------- K1a: sc_s via MFMA (verified R2) ----------------
#define MEs 64
__global__ __launch_bounds__(256, 2) void k_sc_s(
    const float* __restrict__ edge_fea, const float* __restrict__ ohp,
    const u16* __restrict__ W2s, float* __restrict__ out) {
  __shared__ u16 esB[64][136];
  __shared__ float ohL[64][16];
  __shared__ u16 Abuf[64 * 128];
  __shared__ u16 Bbuf[128 * 128];
  const int t = threadIdx.x;
  const int lane = t & 63, ww = t >> 6;
  const int e0 = blockIdx.x * MEs;
  const int nE = min(MEs, E_TOT - e0);

  for (int o = t; o < 64 * 32; o += 256) {
    int e = o >> 5, c4 = (o & 31) << 2;
    float4 x = (e < nE) ? *(const float4*)&edge_fea[(size_t)(e0 + e) * DIM + c4]
                        : make_float4(0.f, 0.f, 0.f, 0.f);
    esB[e][c4 + 0] = f2bf(x.x); esB[e][c4 + 1] = f2bf(x.y);
    esB[e][c4 + 2] = f2bf(x.z); esB[e][c4 + 3] = f2bf(x.w);
  }
  for (int o = t; o < 64 * 16; o += 256) {
    int e = o >> 4, s = o & 15;
    ohL[e][s] = (e < nE) ? ohp[(size_t)(e0 + e) * 16 + s] : 0.f;
  }
  __syncthreads();

  f32x4 acc[4][2];
  #pragma unroll
  for (int a = 0; a < 4; ++a)
    #pragma unroll
    for (int b = 0; b < 2; ++b) acc[a][b] = (f32x4){0.f, 0.f, 0.f, 0.f};

  for (int s = 0; s < 16; ++s) {
    {
      const char* sb = (const char*)W2s + s * 256;
      #pragma unroll
      for (int it = 0; it < 8; ++it) {
        int n = it * 256 + t;
        int u = n >> 4, gp = n & 15, g = gp ^ (u & 7);
        gl_lds16(sb + (size_t)u * 4096 + g * 16, (char*)Bbuf + n * 16);
      }
    }
    #pragma unroll
    for (int it = 0; it < 4; ++it) {
      int n = it * 256 + t;
      int e = n >> 4, gp = n & 15, g = gp ^ (e & 7);
      float ohs = ohL[e][s];
      union { uint4 q; u16 h[8]; } in, ov;
      in.q = *(const uint4*)&esB[e][g * 8];
      #pragma unroll
      for (int j = 0; j < 8; ++j) ov.h[j] = f2bf(bf2f(in.h[j]) * ohs);
      *(uint4*)((char*)Abuf + e * 256 + gp * 16) = ov.q;
    }
    __syncthreads();

    const int cbl = (lane >> 4) << 4;
    #pragma unroll
    for (int ks = 0; ks < 4; ++ks) {
      int cbyte = ks * 64 + cbl;
      bf16x8 bfr[2], afr[4];
      #pragma unroll
      for (int ct = 0; ct < 2; ++ct) {
        int u = ww * 32 + ct * 16 + (lane & 15);
        bfr[ct] = *(const bf16x8*)((const char*)Bbuf + u * 256 + (cbyte ^ ((u & 7) << 4)));
      }
      #pragma unroll
      for (int rt = 0; rt < 4; ++rt) {
        int e = rt * 16 + (lane & 15);
        afr[rt] = *(const bf16x8*)((const char*)Abuf + e * 256 + (cbyte ^ ((e & 7) << 4)));
      }
      #pragma unroll
      for (int rt = 0; rt < 4; ++rt)
        #pragma unroll
        for (int ct = 0; ct < 2; ++ct)
          acc[rt][ct] = __builtin_amdgcn_mfma_f32_16x16x32_bf16(afr[rt], bfr[ct], acc[rt][ct], 0, 0, 0);
    }
    __syncthreads();
  }

  #pragma unroll
  for (int rt = 0; rt < 4; ++rt) {
    int ebase = rt * 16 + ((lane >> 4) << 2);
    #pragma unroll
    for (int ct = 0; ct < 2; ++ct) {
      int u = ww * 32 + ct * 16 + (lane & 15);
      #pragma unroll
      for (int j = 0; j < 4; ++j) {
        int ee = ebase + j;
        if (ee < nE) out[(size_t)(e0 + ee) * DIM + u] = acc[rt][ct][j] * SC_S_SCALE;
      }
    }
  }
}

// ---------------- K1b: sc_v via MFMA (verified R2) ----------------
__global__ __launch_bounds__(256, 2) void k_sc_v(
    const float* __restrict__ edge_fea, const float* __restrict__ ohp,
    const u16* __restrict__ Btv, float* __restrict__ out) {
  __shared__ u16 evT[3][64][72];
  __shared__ float ohL[64][16];
  __shared__ u16 Abuf[192 * 64];
  __shared__ u16 Bbuf[64 * 64];
  const int t = threadIdx.x;
  const int lane = t & 63, ww = t >> 6;
  const int e0 = blockIdx.x * MEs;
  const int nE = min(MEs, E_TOT - e0);

  for (int o = t; o < 64 * 192; o += 256) {
    int e = o / 192, c = o % 192;
    int v = c / 3, m = c % 3;
    float x = (e < nE) ? edge_fea[(size_t)(e0 + e) * DIM + NS + c] : 0.f;
    evT[m][e][v] = f2bf(x);
  }
  for (int o = t; o < 64 * 16; o += 256) {
    int e = o >> 4, s = o & 15;
    ohL[e][s] = (e < nE) ? ohp[(size_t)(e0 + e) * 16 + s] : 0.f;
  }
  __syncthreads();

  f32x4 acc[12];
  #pragma unroll
  for (int a = 0; a < 12; ++a) acc[a] = (f32x4){0.f, 0.f, 0.f, 0.f};

  for (int s = 0; s < 16; ++s) {
    #pragma unroll
    for (int it = 0; it < 2; ++it) {
      int n = it * 256 + t;
      int u = n >> 3, gp = n & 7, g = gp ^ (u & 7);
      gl_lds16((const char*)Btv + (size_t)u * 2048 + s * 128 + g * 16, (char*)Bbuf + n * 16);
    }
    #pragma unroll
    for (int it = 0; it < 6; ++it) {
      int n = it * 256 + t;
      int r = n >> 3, gp = n & 7, g = gp ^ (r & 7);
      int e = r / 3, m = r - e * 3;
      float ohs = ohL[e][s];
      union { uint4 q; u16 h[8]; } in, ov;
      in.q = *(const uint4*)&evT[m][e][g * 8];
      #pragma unroll
      for (int j = 0; j < 8; ++j) ov.h[j] = f2bf(bf2f(in.h[j]) * ohs);
      *(uint4*)((char*)Abuf + r * 128 + gp * 16) = ov.q;
    }
    __syncthreads();

    const int cbl = (lane >> 4) << 4;
    #pragma unroll
    for (int ks = 0; ks < 2; ++ks) {
      int cbyte = ks * 64 + cbl;
      int u = ww * 16 + (lane & 15);
      bf16x8 bfr = *(const bf16x8*)((const char*)Bbuf + u * 128 + (cbyte ^ ((u & 7) << 4)));
      #pragma unroll
      for (int rt = 0; rt < 12; ++rt) {
        int r = rt * 16 + (lane & 15);
        bf16x8 afr = *(const bf16x8*)((const char*)Abuf + r * 128 + (cbyte ^ ((r & 7) << 4)));
        acc[rt] = __builtin_amdgcn_mfma_f32_16x16x32_bf16(afr, bfr, acc[rt], 0, 0, 0);
      }
    }
    __syncthreads();
  }

  #pragma unroll
  for (int rt = 0; rt < 12; ++rt) {
    int rbase = rt * 16 + ((lane >> 4) << 2);
    int u = ww * 16 + (lane & 15);
    #pragma unroll
    for (int j = 0; j < 4; ++j) {
      int r = rbase + j;
      int e = r / 3, m = r - e * 3;
      if (e < nE) out[(size_t)(e0 + e) * DIM + NS + u * 3 + m] = acc[rt][j] * SC_V_SCALE;
    }
  }
}

// ---------------- K2a: pre-linears + mixing (MFMA), writes outs/outv bf16 ----------------
// LDS arena: sin0|sin1|sin2(es->s) 3x16K, vin0|vin1|vin2(ev->v) 3x24K, svh 24K, t1 8K
__global__ __launch_bounds__(512, 1) void k2a(
    const float* __restrict__ node_fea, const float* __restrict__ edge_sh,
    const float* __restrict__ edge_fea, const int* __restrict__ eidx,
    const char* __restrict__ Wpre0T, const float* __restrict__ bpre0,
    const char* __restrict__ Wpre1T, const char* __restrict__ WssT,
    const char* __restrict__ WvsT, const char* __restrict__ WsvT,
    const char* __restrict__ WvvT,
    u16* __restrict__ outsG, u16* __restrict__ outvG) {
  __shared__ char AR[155648];
  __shared__ float shF[64][4];
  __shared__ int iL[64], jL[64];
  const int t = threadIdx.x, lane = t & 63, wv = t >> 6;
  const int l15 = lane & 15, q4 = (lane >> 4) << 2, cbl = (lane >> 4) << 4;
  const int e0 = blockIdx.x * 64;
  const int nE = min(64, E_TOT - e0);
  char* sin2 = AR + 32768;
  char* vin2 = AR + 98304;
  char* svh  = AR + 122880;
  char* t1B  = AR + 147456;

  if (t < 64) { iL[t] = (t < nE) ? eidx[e0 + t] : 0; jL[t] = (t < nE) ? eidx[E_TOT + e0 + t] : 0; }
  for (int o = t; o < 256; o += 512) {
    int e = o >> 2, m = o & 3;
    shF[e][m] = (e < nE) ? edge_sh[(size_t)(e0 + e) * 4 + m] : 0.f;
  }
  __syncthreads();

  // stage edge_fea -> es(sin2), ev(vin2)
  for (int o = t; o < 64 * 80; o += 512) {
    int e = o / 80, q = o % 80;
    float4 x = (e < nE) ? ((const float4*)edge_fea)[(size_t)(e0 + e) * 80 + q]
                        : make_float4(0.f, 0.f, 0.f, 0.f);
    int c = q * 4;
    #pragma unroll
    for (int z = 0; z < 4; ++z) {
      float val = (&x.x)[z]; int cc = c + z;
      if (cc < 128) stb(sin2, e, 256, cc * 2, f2bf(val));
      else { int v = (cc - 128) / 3, m = (cc - 128) % 3; stb(vin2, m * 64 + e, 128, v * 2, f2bf(val)); }
    }
  }
  // stage node gathers -> sin0/sin1, vin0/vin1
  for (int o = t; o < 2 * 64 * 80; o += 512) {
    int p = o / 80, q = o % 80;
    int e = p >> 1, wh = p & 1;
    int n = wh ? jL[e] : iL[e];
    float4 x = (e < nE) ? ((const float4*)node_fea)[(size_t)n * 80 + q]
                        : make_float4(0.f, 0.f, 0.f, 0.f);
    char* sB = AR + wh * 16384;
    char* vB = AR + 49152 + wh * 24576;
    int c = q * 4;
    #pragma unroll
    for (int z = 0; z < 4; ++z) {
      float val = (&x.x)[z]; int cc = c + z;
      if (cc < 128) stb(sB, e, 256, cc * 2, f2bf(val));
      else { int v = (cc - 128) / 3, m = (cc - 128) % 3; stb(vB, m * 64 + e, 128, v * 2, f2bf(val)); }
    }
  }
  __syncthreads();

  // ---- P1: s = es@Wpre0'+b (waves 0-3), v = ev@Wpre1' (waves 4-7)
  f32x4 p1[12];
  #pragma unroll
  for (int a = 0; a < 12; ++a) p1[a] = (f32x4){0.f, 0.f, 0.f, 0.f};
  if (wv < 4) {
    for (int kc = 0; kc < 4; ++kc) {
      int cbyte = kc * 64 + cbl;
      bf16x8 b0 = *(const bf16x8*)(Wpre0T + (size_t)(wv * 32 + l15) * 256 + cbyte);
      bf16x8 b1 = *(const bf16x8*)(Wpre0T + (size_t)(wv * 32 + 16 + l15) * 256 + cbyte);
      #pragma unroll
      for (int mt = 0; mt < 4; ++mt) {
        bf16x8 a = ldb8(sin2, mt * 16 + l15, 256, cbyte);
        p1[mt * 2 + 0] = __builtin_amdgcn_mfma_f32_16x16x32_bf16(a, b0, p1[mt * 2 + 0], 0, 0, 0);
        p1[mt * 2 + 1] = __builtin_amdgcn_mfma_f32_16x16x32_bf16(a, b1, p1[mt * 2 + 1], 0, 0, 0);
      }
    }
  } else {
    for (int kc = 0; kc < 2; ++kc) {
      int cbyte = kc * 64 + cbl;
      bf16x8 b = *(const bf16x8*)(Wpre1T + (size_t)((wv - 4) * 16 + l15) * 128 + cbyte);
      #pragma unroll
      for (int mt = 0; mt < 12; ++mt) {
        bf16x8 a = ldb8(vin2, mt * 16 + l15, 128, cbyte);
        p1[mt] = __builtin_amdgcn_mfma_f32_16x16x32_bf16(a, b, p1[mt], 0, 0, 0);
      }
    }
  }
  __syncthreads();  // all reads of es/ev done
  if (wv < 4) {
    #pragma unroll
    for (int mt = 0; mt < 4; ++mt)
      #pragma unroll
      for (int nt = 0; nt < 2; ++nt) {
        int u = wv * 32 + nt * 16 + l15;
        float bias = bpre0[u];
        #pragma unroll
        for (int j = 0; j < 4; ++j) {
          int e = mt * 16 + q4 + j;
          stb(sin2, e, 256, u * 2, f2bf(p1[mt * 2 + nt][j] + bias));
        }
      }
  } else {
    #pragma unroll
    for (int mt = 0; mt < 12; ++mt) {
      int u = (wv - 4) * 16 + l15;
      #pragma unroll
      for (int j = 0; j < 4; ++j) {
        int r = mt * 16 + q4 + j;
        stb(vin2, r, 128, u * 2, f2bf(p1[mt][j]));
      }
    }
  }
  __syncthreads();

  // ---- P2: svh[e][k] = sum_m vin[k][m]*sh1[m]
  for (int o = t; o < 64 * 192; o += 512) {
    int e = o / 192, k = o % 192;
    int buf = k >> 6, kk = k & 63;
    const char* vb = AR + 49152 + buf * 24576;
    float s = 0.f;
    #pragma unroll
    for (int m = 0; m < 3; ++m) {
      u16 hv = *(const u16*)(vb + (m * 64 + e) * 128 + ((kk * 2) ^ ((e & 7) << 4)));
      s += bf2f(hv) * shF[e][m + 1];
    }
    stb(svh, e, 384, k * 2, f2bf(s));
  }

  // ---- P3a: t1 = s_in@Wsv' (16 tiles, 2/wave)
  {
    f32x4 at[2];
    at[0] = (f32x4){0.f, 0.f, 0.f, 0.f}; at[1] = at[0];
    int tmt[2], tnt[2];
    #pragma unroll
    for (int i = 0; i < 2; ++i) { int tile = wv * 2 + i; tmt[i] = tile >> 2; tnt[i] = tile & 3; }
    for (int kc = 0; kc < 12; ++kc) {
      int cbyte = (kc & 3) * 64 + cbl;
      const char* ab = AR + (kc >> 2) * 16384;
      #pragma unroll
      for (int i = 0; i < 2; ++i) {
        bf16x8 a = ldb8(ab, tmt[i] * 16 + l15, 256, cbyte);
        bf16x8 b = *(const bf16x8*)(WsvT + (size_t)(tnt[i] * 16 + l15) * 768 + kc * 64 + cbl);
        at[i] = __builtin_amdgcn_mfma_f32_16x16x32_bf16(a, b, at[i], 0, 0, 0);
      }
    }
    #pragma unroll
    for (int i = 0; i < 2; ++i) {
      int u = tnt[i] * 16 + l15;
      #pragma unroll
      for (int j = 0; j < 4; ++j) {
        int e = tmt[i] * 16 + q4 + j;
        stb(t1B, e, 128, u * 2, f2bf(at[i][j]));
      }
    }
  }
  __syncthreads();  // svh + t1 ready

  // ---- P3b: out_s (6 acc/wave) then out_v (6 acc/wave)
  {
    f32x4 as_[6];
    #pragma unroll
    for (int a = 0; a < 6; ++a) as_[a] = (f32x4){0.f, 0.f, 0.f, 0.f};
    const int smt = wv >> 1, snb = (wv & 1) * 6;
    for (int kc = 0; kc < 12; ++kc) {
      int cbyte = (kc & 3) * 64 + cbl;
      bf16x8 a = ldb8(AR + (kc >> 2) * 16384, smt * 16 + l15, 256, cbyte);
      #pragma unroll
      for (int nt = 0; nt < 6; ++nt) {
        bf16x8 b = *(const bf16x8*)(WssT + (size_t)((snb + nt) * 16 + l15) * 768 + kc * 64 + cbl);
        as_[nt] = __builtin_amdgcn_mfma_f32_16x16x32_bf16(a, b, as_[nt], 0, 0, 0);
      }
    }
    #pragma unroll
    for (int nt = 0; nt < 6; ++nt)
      #pragma unroll
      for (int j = 0; j < 4; ++j) as_[nt][j] *= shF[smt * 16 + q4 + j][0];
    for (int kc = 0; kc < 6; ++kc) {
      int cbyte = kc * 64 + cbl;
      bf16x8 a = ldb8(svh, smt * 16 + l15, 384, cbyte);
      #pragma unroll
      for (int nt = 0; nt < 6; ++nt) {
        bf16x8 b = *(const bf16x8*)(WvsT + (size_t)((snb + nt) * 16 + l15) * 384 + kc * 64 + cbl);
        as_[nt] = __builtin_amdgcn_mfma_f32_16x16x32_bf16(a, b, as_[nt], 0, 0, 0);
      }
    }
    #pragma unroll
    for (int nt = 0; nt < 6; ++nt) {
      int u = (snb + nt) * 16 + l15;
      #pragma unroll
      for (int j = 0; j < 4; ++j) {
        int e = smt * 16 + q4 + j;
        if (e < nE) outsG[(size_t)(e0 + e) * 192 + u] = f2bf(as_[nt][j]);
      }
    }

    f32x4 av[6];
    #pragma unroll
    for (int a = 0; a < 6; ++a) av[a] = (f32x4){0.f, 0.f, 0.f, 0.f};
    for (int kc = 0; kc < 6; ++kc) {
      int cbyte = (kc & 1) * 64 + cbl;
      const char* vb = AR + 49152 + (kc >> 1) * 24576;
      #pragma unroll
      for (int i = 0; i < 6; ++i) {
        int tile = wv * 6 + i, mt = tile >> 2, nt = tile & 3;
        bf16x8 a = ldb8(vb, mt * 16 + l15, 128, cbyte);
        bf16x8 b = *(const bf16x8*)(WvvT + (size_t)(nt * 16 + l15) * 384 + kc * 64 + cbl);
        av[i] = __builtin_amdgcn_mfma_f32_16x16x32_bf16(a, b, av[i], 0, 0, 0);
      }
    }
    #pragma unroll
    for (int i = 0; i < 6; ++i) {
      int tile = wv * 6 + i, mt = tile >> 2, nt = tile & 3;
      int u = nt * 16 + l15;
      #pragma unroll
      for (int j = 0; j < 4; ++j) {
        int r = mt * 16 + q4 + j;
        int m = r >> 6, e = r & 63;
        float t1v = bf2f(*(const u16*)(t1B + e * 128 + ((u * 2) ^ ((e & 7) << 4))));
        float val = av[i][j] * shF[e][0] + t1v * shF[e][1 + m];
        if (e < nE) outvG[(size_t)(e0 + e) * 192 + m * 64 + u] = f2bf(val);
      }
    }
  }
}

// ---------------- K2b: MLP + gating + post linears, accumulates onto sc in d_out ----------
// arena: [0,16K) elen->h1(0,8K)+h2(8K,16K)->zsA ; [16K,40K) wB ; [40K,64K) zvA
__global__ __launch_bounds__(256, 2) void k2b(
    const float* __restrict__ elen,
    const char* __restrict__ Wf1T, const float* __restrict__ bf1,
    const char* __restrict__ Wf2T, const float* __restrict__ bf2,
    const char* __restrict__ Wf3T, const float* __restrict__ bf3,
    const char* __restrict__ Wpost0T, const float* __restrict__ bpost0,
    const char* __restrict__ Wpost1T,
    const u16* __restrict__ outsG, const u16* __restrict__ outvG,
    float* __restrict__ out) {
  __shared__ char AR[65536];
  const int t = threadIdx.x, lane = t & 63, wv = t >> 6;
  const int l15 = lane & 15, q4 = (lane >> 4) << 2, cbl = (lane >> 4) << 4;
  const int e0 = blockIdx.x * 64;
  const int nE = min(64, E_TOT - e0);
  char* elB = AR;
  char* h1B = AR;
  char* h2B = AR + 8192;
  char* wB  = AR + 16384;
  char* zsA = AR;
  char* zvA = AR + 40960;

  for (int o = t; o < 64 * 32; o += 256) {
    int e = o >> 5, q = o & 31;
    float4 x = (e < nE) ? ((const float4*)elen)[(size_t)(e0 + e) * 32 + q]
                        : make_float4(0.f, 0.f, 0.f, 0.f);
    int c = q * 4;
    stb(elB, e, 256, (c + 0) * 2, f2bf(x.x)); stb(elB, e, 256, (c + 1) * 2, f2bf(x.y));
    stb(elB, e, 256, (c + 2) * 2, f2bf(x.z)); stb(elB, e, 256, (c + 3) * 2, f2bf(x.w));
  }
  __syncthreads();

  // h1 = silu(elen@Wf1 + bf1)
  {
    f32x4 acc[4];
    #pragma unroll
    for (int a = 0; a < 4; ++a) acc[a] = (f32x4){0.f, 0.f, 0.f, 0.f};
    for (int kc = 0; kc < 4; ++kc) {
      int cbyte = kc * 64 + cbl;
      bf16x8 b = *(const bf16x8*)(Wf1T + (size_t)(wv * 16 + l15) * 256 + cbyte);
      #pragma unroll
      for (int mt = 0; mt < 4; ++mt) {
        bf16x8 a = ldb8(elB, mt * 16 + l15, 256, cbyte);
        acc[mt] = __builtin_amdgcn_mfma_f32_16x16x32_bf16(a, b, acc[mt], 0, 0, 0);
      }
    }
    __syncthreads();
    int u = wv * 16 + l15;
    float bias = bf1[u];
    #pragma unroll
    for (int mt = 0; mt < 4; ++mt)
      #pragma unroll
      for (int j = 0; j < 4; ++j)
        stb(h1B, mt * 16 + q4 + j, 128, u * 2, f2bf(siluf_(acc[mt][j] + bias)));
  }
  __syncthreads();
  // h2 = silu(h1@Wf2 + bf2)
  {
    f32x4 acc[4];
    #pragma unroll
    for (int a = 0; a < 4; ++a) acc[a] = (f32x4){0.f, 0.f, 0.f, 0.f};
    for (int kc = 0; kc < 2; ++kc) {
      int cbyte = kc * 64 + cbl;
      bf16x8 b = *(const bf16x8*)(Wf2T + (size_t)(wv * 16 + l15) * 128 + cbyte);
      #pragma unroll
      for (int mt = 0; mt < 4; ++mt) {
        bf16x8 a = ldb8(h1B, mt * 16 + l15, 128, cbyte);
        acc[mt] = __builtin_amdgcn_mfma_f32_16x16x32_bf16(a, b, acc[mt], 0, 0, 0);
      }
    }
    __syncthreads();
    int u = wv * 16 + l15;
    float bias = bf2[u];
    #pragma unroll
    for (int mt = 0; mt < 4; ++mt)
      #pragma unroll
      for (int j = 0; j < 4; ++j)
        stb(h2B, mt * 16 + q4 + j, 128, u * 2, f2bf(siluf_(acc[mt][j] + bias)));
  }
  __syncthreads();
  // w = h2@Wf3 + bf3  -> wB plain [64][192]
  {
    f32x4 acc[12];
    #pragma unroll
    for (int a = 0; a < 12; ++a) acc[a] = (f32x4){0.f, 0.f, 0.f, 0.f};
    for (int kc = 0; kc < 2; ++kc) {
      int cbyte = kc * 64 + cbl;
      #pragma unroll
      for (int mt = 0; mt < 4; ++mt) {
        bf16x8 a = ldb8(h2B, mt * 16 + l15, 128, cbyte);
        #pragma unroll
        for (int nt = 0; nt < 3; ++nt) {
          bf16x8 b = *(const bf16x8*)(Wf3T + (size_t)((wv * 3 + nt) * 16 + l15) * 128 + cbyte);
          acc[mt * 3 + nt] = __builtin_amdgcn_mfma_f32_16x16x32_bf16(a, b, acc[mt * 3 + nt], 0, 0, 0);
        }
      }
    }
    __syncthreads();
    #pragma unroll
    for (int mt = 0; mt < 4; ++mt)
      #pragma unroll
      for (int nt = 0; nt < 3; ++nt) {
        int u = (wv * 3 + nt) * 16 + l15;
        float bias = bf3[u];
        #pragma unroll
        for (int j = 0; j < 4; ++j) {
          int e = mt * 16 + q4 + j;
          *(u16*)(wB + e * 384 + u * 2) = f2bf(acc[mt * 3 + nt][j] + bias);
        }
      }
  }
  __syncthreads();
  // gating
  for (int o = t; o < 64 * 128; o += 256) {
    int e = o >> 7, u = o & 127;
    float os = (e < nE) ? bf2f(outsG[(size_t)(e0 + e) * 192 + u]) : 0.f;
    float wv_ = bf2f(*(const u16*)(wB + e * 384 + u * 2));
    stb(zsA, e, 256, u * 2, f2bf(siluf_(os) * wv_));
  }
  for (int o = t; o < 192 * 64; o += 256) {
    int r = o >> 6, u = o & 63;
    int m = r >> 6, e = r & 63;
    float ov = 0.f, gate = 0.f, wv_ = 0.f;
    if (e < nE) {
      ov = bf2f(outvG[(size_t)(e0 + e) * 192 + m * 64 + u]);
      gate = sigmoidf_(bf2f(outsG[(size_t)(e0 + e) * 192 + 128 + u]));
      wv_ = bf2f(*(const u16*)(wB + e * 384 + (128 + u) * 2));
    }
    stb(zvA, r, 128, u * 2, f2bf(ov * gate * wv_));
  }
  __syncthreads();
  // post0: zs@Wpost0' + bpost0, accumulate into out
  {
    f32x4 acc[8];
    #pragma unroll
    for (int a = 0; a < 8; ++a) acc[a] = (f32x4){0.f, 0.f, 0.f, 0.f};
    for (int kc = 0; kc < 4; ++kc) {
      int cbyte = kc * 64 + cbl;
      #pragma unroll
      for (int nt = 0; nt < 2; ++nt) {
        bf16x8 b = *(const bf16x8*)(Wpost0T + (size_t)((wv * 2 + nt) * 16 + l15) * 256 + cbyte);
        #pragma unroll
        for (int mt = 0; mt < 4; ++mt) {
          bf16x8 a = ldb8(zsA, mt * 16 + l15, 256, cbyte);
          acc[mt * 2 + nt] = __builtin_amdgcn_mfma_f32_16x16x32_bf16(a, b, acc[mt * 2 + nt], 0, 0, 0);
        }
      }
    }
    #pragma unroll
    for (int mt = 0; mt < 4; ++mt)
      #pragma unroll
      for (int nt = 0; nt < 2; ++nt) {
        int u = (wv * 2 + nt) * 16 + l15;
        float bias = bpost0[u];
        #pragma unroll
        for (int j = 0; j < 4; ++j) {
          int e = mt * 16 + q4 + j;
          if (e < nE) {
            size_t o = (size_t)(e0 + e) * DIM + u;
            out[o] = out[o] + acc[mt * 2 + nt][j] + bias;
          }
        }
      }
  }
  // post1: zv@Wpost1', accumulate into out
  {
    f32x4 acc[12];
    #pragma unroll
    for (int a = 0; a < 12; ++a) acc[a] = (f32x4){0.f, 0.f, 0.f, 0.f};
    for (int kc = 0; kc < 2; ++kc) {
      int cbyte = kc * 64 + cbl;
      bf16x8 b = *(const bf16x8*)(Wpost1T + (size_t)(wv * 16 + l15) * 128 + cbyte);
      #pragma unroll
      for (int mt = 0; mt < 12; ++mt) {
        bf16x8 a = ldb8(zvA, mt * 16 + l15, 128, cbyte);
        acc[mt] = __builtin_amdgcn_mfma_f32_16x16x32_bf16(a, b, acc[mt], 0, 0, 0);
      }
    }
    int u = wv * 16 + l15;
    #pragma unroll
    for (int mt = 0; mt < 12; ++mt)
      #pragma unroll
      for (int j = 0; j < 4; ++j) {
        int r = mt * 16 + q4 + j;
        int m = r >> 6, e = r & 63;
        if (e < nE) {
          size_t o = (size_t)(e0 + e) * DIM + 128 + u * 3 + m;
          out[o] = out[o] + acc[mt][j];
        }
      }
  }
}

// ---------------- fallback f32 k_main (verified R2) ----------------
__global__ __launch_bounds__(512, 1) void k_main_f32(
    const float* __restrict__ node_fea, const float* __restrict__ edge_sh,
    const float* __restrict__ edge_fea, const float* __restrict__ elen,
    const int* __restrict__ eidx,
    const float* __restrict__ Wpre0, const float* __restrict__ bpre0,
    const float* __restrict__ Wpre1,
    const float* __restrict__ Wss, const float* __restrict__ Wvs,
    const float* __restrict__ Wsv, const float* __restrict__ Wvv,
    const float* __restrict__ Wf1, const float* __restrict__ bf1,
    const float* __restrict__ Wf2, const float* __restrict__ bf2,
    const float* __restrict__ Wf3, const float* __restrict__ bf3,
    const float* __restrict__ Wpost0, const float* __restrict__ bpost0,
    const float* __restrict__ Wpost1,
    float* __restrict__ out) {
  __shared__ float sinL[384][ET];
  __shared__ float vinL[576][ET];
  __shared__ float esL[128][ET];
  __shared__ float evL[192][ET];
  __shared__ float elenL[128][ET];
  __shared__ float shL[4][ET];
  __shared__ float svhL[192][ET];
  __shared__ float outsL[192][ET];
  __shared__ float outvL[192][ET];
  __shared__ float t1L[64][ET];
  __shared__ float h1L[64][ET];
  __shared__ float h2L[64][ET];
  __shared__ float wL[192][ET];
  __shared__ int iL[ET], jL[ET];

  const int t = threadIdx.x;
  const int e0 = blockIdx.x * ET;

  if (t < ET) { iL[t] = eidx[e0 + t]; jL[t] = eidx[E_TOT + e0 + t]; }
  __syncthreads();

  for (int o = t; o < ET * DIM; o += 512) {
    int e = o / DIM, c = o % DIM;
    float x = edge_fea[(size_t)(e0 + e) * DIM + c];
    if (c < NS) esL[c][e] = x; else evL[c - NS][e] = x;
  }
  for (int o = t; o < 2 * ET * DIM; o += 512) {
    int p = o / DIM, c = o % DIM;
    int e = p >> 1, wh = p & 1;
    int node = wh ? jL[e] : iL[e];
    float x = node_fea[(size_t)node * DIM + c];
    if (c < NS) sinL[wh * NS + c][e] = x; else vinL[wh * 192 + (c - NS)][e] = x;
  }
  for (int o = t; o < ET * 128; o += 512) {
    int e = o >> 7, c = o & 127;
    elenL[c][e] = elen[(size_t)(e0 + e) * 128 + c];
  }
  if (t < ET * 4) { int e = t >> 2, m = t & 3; shL[m][e] = edge_sh[(size_t)(e0 + e) * 4 + m]; }
  __syncthreads();

  {
    const int u = t & 127, eh = t >> 7;
    float a[4] = {0, 0, 0, 0};
    for (int k = 0; k < 128; ++k) {
      float w = Wpre0[k * 128 + u];
      const float4 x = *(const float4*)&esL[k][eh * 4];
      a[0] += x.x * w; a[1] += x.y * w; a[2] += x.z * w; a[3] += x.w * w;
    }
    float b = bpre0[u];
    #pragma unroll
    for (int q = 0; q < 4; ++q) sinL[256 + u][eh * 4 + q] = a[q] * INV_SQRT128 + b;
  }
  if (t < 384) {
    const int row = t % 192, eh = t / 192;
    const int u = row / 3, m = row % 3;
    float a[8] = {0, 0, 0, 0, 0, 0, 0, 0};
    for (int k = 0; k < 64; ++k) {
      float w = Wpre1[k * 64 + u];
      const float4 x0 = *(const float4*)&evL[k * 3 + m][eh * 8];
      const float4 x1 = *(const float4*)&evL[k * 3 + m][eh * 8 + 4];
      a[0] += x0.x * w; a[1] += x0.y * w; a[2] += x0.z * w; a[3] += x0.w * w;
      a[4] += x1.x * w; a[5] += x1.y * w; a[6] += x1.z * w; a[7] += x1.w * w;
    }
    #pragma unroll
    for (int q = 0; q < 8; ++q) vinL[384 + row][eh * 8 + q] = a[q] * INV_8;
  }
  __syncthreads();

  for (int o = t; o < 192 * ET; o += 512) {
    int e = o & 15, K = o >> 4;
    svhL[K][e] = vinL[K * 3 + 0][e] * shL[1][e] + vinL[K * 3 + 1][e] * shL[2][e] +
                 vinL[K * 3 + 2][e] * shL[3][e];
  }
  __syncthreads();

  if (t < 384) {
    const int n = t % 192, eh = t / 192;
    float a[8] = {0, 0, 0, 0, 0, 0, 0, 0};
    float b[8] = {0, 0, 0, 0, 0, 0, 0, 0};
    for (int k = 0; k < 384; ++k) {
      float w = Wss[k * 192 + n];
      const float4 x0 = *(const float4*)&sinL[k][eh * 8];
      const float4 x1 = *(const float4*)&sinL[k][eh * 8 + 4];
      a[0] += x0.x * w; a[1] += x0.y * w; a[2] += x0.z * w; a[3] += x0.w * w;
      a[4] += x1.x * w; a[5] += x1.y * w; a[6] += x1.z * w; a[7] += x1.w * w;
    }
    for (int k = 0; k < 192; ++k) {
      float w = Wvs[k * 192 + n];
      const float4 x0 = *(const float4*)&svhL[k][eh * 8];
      const float4 x1 = *(const float4*)&svhL[k][eh * 8 + 4];
      b[0] += x0.x * w; b[1] += x0.y * w; b[2] += x0.z * w; b[3] += x0.w * w;
      b[4] += x1.x * w; b[5] += x1.y * w; b[6] += x1.z * w; b[7] += x1.w * w;
    }
    #pragma unroll
    for (int q = 0; q < 8; ++q) {
      int e = eh * 8 + q;
      outsL[n][e] = (shL[0][e] * a[q] * INV_S384 + b[q] * INV_24) * RSQRT2;
    }
  } else {
    const int tt = t - 384;
    const int u = tt & 63, eh = tt >> 6;
    float a[8] = {0, 0, 0, 0, 0, 0, 0, 0};
    for (int k = 0; k < 384; ++k) {
      float w = Wsv[k * 64 + u];
      const float4 x0 = *(const float4*)&sinL[k][eh * 8];
      const float4 x1 = *(const float4*)&sinL[k][eh * 8 + 4];
      a[0] += x0.x * w; a[1] += x0.y * w; a[2] += x0.z * w; a[3] += x0.w * w;
      a[4] += x1.x * w; a[5] += x1.y * w; a[6] += x1.z * w; a[7] += x1.w * w;
    }
    #pragma unroll
    for (int q = 0; q < 8; ++q) t1L[u][eh * 8 + q] = a[q];
  }
  __syncthreads();

  if (t < 384) {
    const int row = t % 192, eh = t / 192;
    const int u = row / 3, m = row % 3;
    float a[8] = {0, 0, 0, 0, 0, 0, 0, 0};
    for (int K = 0; K < 192; ++K) {
      float w = Wvv[K * 64 + u];
      const float4 x0 = *(const float4*)&vinL[K * 3 + m][eh * 8];
      const float4 x1 = *(const float4*)&vinL[K * 3 + m][eh * 8 + 4];
      a[0] += x0.x * w; a[1] += x0.y * w; a[2] += x0.z * w; a[3] += x0.w * w;
      a[4] += x1.x * w; a[5] += x1.y * w; a[6] += x1.z * w; a[7] += x1.w * w;
    }
    #pragma unroll
    for (int q = 0; q < 8; ++q) {
      int e = eh * 8 + q;
      outvL[row][e] = (t1L[u][e] * shL[1 + m][e] * INV_S384 + shL[0][e] * a[q] * INV_S192) * RSQRT2;
    }
  } else {
    const int tt = t - 384;
    const int u = tt & 63, eh = tt >> 6;
    float a[8] = {0, 0, 0, 0, 0, 0, 0, 0};
    for (int k = 0; k < 128; ++k) {
      float w = Wf1[k * 64 + u];
      const float4 x0 = *(const float4*)&elenL[k][eh * 8];
      const float4 x1 = *(const float4*)&elenL[k][eh * 8 + 4];
      a[0] += x0.x * w; a[1] += x0.y * w; a[2] += x0.z * w; a[3] += x0.w * w;
      a[4] += x1.x * w; a[5] += x1.y * w; a[6] += x1.z * w; a[7] += x1.w * w;
    }
    float b = bf1[u];
    #pragma unroll
    for (int q = 0; q < 8; ++q) h1L[u][eh * 8 + q] = siluf_(a[q] + b);
  }
  __syncthreads();

  {
    const int u = t & 63, eh = t >> 6;
    float a0 = 0, a1 = 0;
    for (int k = 0; k < 64; ++k) {
      float w = Wf2[k * 64 + u];
      const float2 x = *(const float2*)&h1L[k][eh * 2];
      a0 += x.x * w; a1 += x.y * w;
    }
    float b = bf2[u];
    h2L[u][eh * 2 + 0] = siluf_(a0 + b);
    h2L[u][eh * 2 + 1] = siluf_(a1 + b);
  }
  __syncthreads();

  if (t < 384) {
    const int n = t % 192, eh = t / 192;
    float a[8] = {0, 0, 0, 0, 0, 0, 0, 0};
    for (int k = 0; k < 64; ++k) {
      float w = Wf3[k * 192 + n];
      const float4 x0 = *(const float4*)&h2L[k][eh * 8];
      const float4 x1 = *(const float4*)&h2L[k][eh * 8 + 4];
      a[0] += x0.x * w; a[1] += x0.y * w; a[2] += x0.z * w; a[3] += x0.w * w;
      a[4] += x1.x * w; a[5] += x1.y * w; a[6] += x1.z * w; a[7] += x1.w * w;
    }
    float b = bf3[n];
    #pragma unroll
    for (int q = 0; q < 8; ++q) wL[n][eh * 8 + q] = a[q] + b;
  }
  __syncthreads();

  for (int o = t; o < 128 * ET; o += 512) {
    int e = o & 15, u = o >> 4;
    esL[u][e] = siluf_(outsL[u][e]) * wL[u][e];
  }
  for (int o = t; o < 192 * ET; o += 512) {
    int e = o & 15, row = o >> 4;
    int u = row / 3;
    evL[row][e] = outvL[row][e] * sigmoidf_(outsL[128 + u][e]) * wL[128 + u][e];
  }
  __syncthreads();

  {
    const int u = t & 127, eh = t >> 7;
    float a[4] = {0, 0, 0, 0};
    for (int k = 0; k < 128; ++k) {
      float w = Wpost0[k * 128 + u];
      const float4 x = *(const float4*)&esL[k][eh * 4];
      a[0] += x.x * w; a[1] += x.y * w; a[2] += x.z * w; a[3] += x.w * w;
    }
    float b = bpost0[u];
    #pragma unroll
    for (int q = 0; q < 4; ++q) {
      size_t o = (size_t)(e0 + eh * 4 + q) * DIM + u;
      out[o] = a[q] * INV_SQRT128 + b + out[o];
    }
  }
  if (t < 384) {
    const int row = t % 192, eh = t / 192;
    const int u = row / 3, m = row % 3;
    float a[8] = {0, 0, 0, 0, 0, 0, 0, 0};
    for (int k = 0; k < 64; ++k) {
      float w = Wpost1[k * 64 + u];
      const float4 x0 = *(const float4*)&evL[k * 3 + m][eh * 8];
      const float4 x1 = *(const float4*)&evL[k * 3 + m][eh * 8 + 4];
      a[0] += x0.x * w; a[1] += x0.y * w; a[2] += x0.z * w; a[3] += x0.w * w;
      a[4] += x1.x * w; a[5] += x1.y * w; a[6] += x1.z * w; a[7] += x1.w * w;
    }
    #pragma unroll
    for (int q = 0; q < 8; ++q) {
      size_t o = (size_t)(e0 + eh * 8 + q) * DIM + NS + row;
      out[o] = a[q] * INV_8 + out[o];
    }
  }
}

// ---------------- K3: group statistics ----------------
__global__ __launch_bounds__(256) void k_stats(
    const float* __restrict__ out, const int* __restrict__ eidx,
    const int* __restrict__ batch, float* __restrict__ stats) {
  __shared__ float gacc[16][4];
  const int t = threadIdx.x;
  if (t < 64) ((float*)gacc)[t] = 0.0f;
  __syncthreads();
  const int el = t >> 4, l = t & 15;
  for (int ebase = blockIdx.x * 16; ebase < E_TOT; ebase += gridDim.x * 16) {
    int e = ebase + el;
    const float* z = out + (size_t)e * DIM;
    float s1 = 0, s2 = 0, s2v = 0;
    for (int c = l; c < NS; c += 16) { float x = z[c]; s1 += x; s2 += x * x; }
    for (int c = NS + l; c < DIM; c += 16) { float x = z[c]; s2v += x * x; }
    #pragma unroll
    for (int msk = 8; msk; msk >>= 1) {
      s1 += __shfl_xor(s1, msk);
      s2 += __shfl_xor(s2, msk);
      s2v += __shfl_xor(s2v, msk);
    }
    if (l == 0) {
      int g = batch[eidx[e]];
      atomicAdd(&gacc[g][0], 1.0f);
      atomicAdd(&gacc[g][1], s1);
      atomicAdd(&gacc[g][2], s2);
      atomicAdd(&gacc[g][3], s2v);
    }
  }
  __syncthreads();
  if (t < 64) {
    float v = gacc[t >> 2][t & 3];
    if (v != 0.0f) atomicAdd(&stats[(t >> 2) * 16 + (t & 3)], v);
  }
}

// ---------------- K4: normalize + residual ----------------
__global__ __launch_bounds__(256) void k_norm(
    const float* __restrict__ edge_fea, const int* __restrict__ eidx,
    const int* __restrict__ batch, const float* __restrict__ stats,
    const float* __restrict__ gamma_s, const float* __restrict__ beta_s,
    const float* __restrict__ gamma_v, float* __restrict__ out) {
  __shared__ float meanL[16], invsL[16], invvL[16];
  __shared__ int gL[ET];
  const int t = threadIdx.x;
  const int e0 = blockIdx.x * ET;
  if (t < 16) {
    float cnt = fmaxf(stats[t * 16 + 0], 1.0f);
    float m = stats[t * 16 + 1] / (cnt * 128.0f);
    float var = stats[t * 16 + 2] / (cnt * 128.0f) - m * m;
    meanL[t] = m;
    invsL[t] = rsqrtf(var + 1e-5f);
    invvL[t] = rsqrtf(stats[t * 16 + 3] / (cnt * 192.0f) + 1e-5f);
  }
  if (t >= 32 && t < 32 + ET) gL[t - 32] = batch[eidx[e0 + t - 32]];
  __syncthreads();
  for (int o = t; o < ET * DIM; o += 256) {
    int e = o / DIM, c = o % DIM;
    int g = gL[e];
    size_t idx = (size_t)(e0 + e) * DIM + c;
    float z = out[idx];
    float r;
    if (c < NS) r = (z - meanL[g]) * invsL[g] * gamma_s[c] + beta_s[c];
    else r = z * invvL[g] * gamma_v[(c - NS) / 3];
    out[idx] = r + edge_fea[idx];
  }
}

extern "C" void kernel_launch(void* const* d_in, const int* in_sizes, int n_in,
                              void* d_out, int out_size, void* d_ws, size_t ws_size,
                              hipStream_t stream) {
  const float* node_fea = (const float*)d_in[0];
  const float* edge_oh  = (const float*)d_in[1];
  const float* edge_sh  = (const float*)d_in[2];
  const float* edge_fea = (const float*)d_in[3];
  const float* elen     = (const float*)d_in[4];
  const int*   eidx     = (const int*)d_in[5];
  const int*   batch    = (const int*)d_in[6];
  const float* Wsc_s    = (const float*)d_in[7];
  const float* Wsc_v    = (const float*)d_in[8];
  const float* Wpre0    = (const float*)d_in[9];
  const float* bpre0    = (const float*)d_in[10];
  const float* Wpre1    = (const float*)d_in[11];
  const float* Wss      = (const float*)d_in[12];
  const float* Wvs      = (const float*)d_in[13];
  const float* Wsv      = (const float*)d_in[14];
  const float* Wvv      = (const float*)d_in[15];
  const float* Wf1      = (const float*)d_in[16];
  const float* bf1      = (const float*)d_in[17];
  const float* Wf2      = (const float*)d_in[18];
  const float* bf2      = (const float*)d_in[19];
  const float* Wf3      = (const float*)d_in[20];
  const float* bf3      = (const float*)d_in[21];
  const float* Wpost0   = (const float*)d_in[22];
  const float* bpost0   = (const float*)d_in[23];
  const float* Wpost1   = (const float*)d_in[24];
  const float* gamma_s  = (const float*)d_in[25];
  const float* beta_s   = (const float*)d_in[26];
  const float* gamma_v  = (const float*)d_in[27];
  float* out = (float*)d_out;

  char* ws = (char*)d_ws;
  float* stats = (float*)ws;
  u16* wbf = (u16*)(ws + OFF_WBF);
  const char* W2s     = (const char*)(wbf);
  const char* Btv     = (const char*)(wbf + C1);
  const char* Wpre0T  = (const char*)(wbf + C1);  // placeholder fix below
  // pointer table into the bf16 weight block
  const char* pW2s    = (const char*)(wbf + 0);
  const char* pBtv    = (const char*)(wbf + C0);
  const char* pWpre0T = (const char*)(wbf + C1);
  const char* pWpre1T = (const char*)(wbf + C2);
  const char* pWssT   = (const char*)(wbf + C3);
  const char* pWvsT   = (const char*)(wbf + C4);
  const char* pWsvT   = (const char*)(wbf + C5);
  const char* pWvvT   = (const char*)(wbf + C6);
  const char* pWf1T   = (const char*)(wbf + C7);
  const char* pWf2T   = (const char*)(wbf + C8);
  const char* pWf3T   = (const char*)(wbf + C9);
  const char* pWpost0T= (const char*)(wbf + C10);
  const char* pWpost1T= (const char*)(wbf + C11);
  (void)W2s; (void)Btv; (void)Wpre0T;

  const int nblk16 = E_TOT / ET;
  const int nblk64 = (E_TOT + MEs - 1) / MEs;
  const bool full = (ws_size >= (size_t)WS_NEED);
  const int nlim = full ? C12 : C1;

  hipMemsetAsync(stats, 0, 16 * 16 * sizeof(float), stream);
  k_prep<<<(C12 + 255) / 256, 256, 0, stream>>>(Wsc_s, Wsc_v, Wpre0, Wpre1, Wss, Wvs, Wsv, Wvv,
                                                Wf1, Wf2, Wf3, Wpost0, Wpost1, wbf, nlim);
  k_sc_s<<<nblk64, 256, 0, stream>>>(edge_fea, edge_oh, (const u16*)pW2s, out);
  k_sc_v<<<nblk64, 256, 0, stream>>>(edge_fea, edge_oh, (const u16*)pBtv, out);
  if (full) {
    u16* outsG = (u16*)(ws + OFF_OUTS);
    u16* outvG = (u16*)(ws + OFF_OUTV);
    k2a<<<nblk64, 512, 0, stream>>>(node_fea, edge_sh, edge_fea, eidx,
                                    pWpre0T, bpre0, pWpre1T, pWssT, pWvsT, pWsvT, pWvvT,
                                    outsG, outvG);
    k2b<<<nblk64, 256, 0, stream>>>(elen, pWf1T, bf1, pWf2T, bf2, pWf3T, bf3,
                                    pWpost0T, bpost0, pWpost1T, outsG, outvG, out);
  } else {
    k_main_f32<<<nblk16, 512, 0, stream>>>(node_fea, edge_sh, edge_fea, elen, eidx,
                                           Wpre0, bpre0, Wpre1, Wss, Wvs, Wsv, Wvv,
                                           Wf1, bf1, Wf2, bf2, Wf3, bf3,
                                           Wpost0, bpost0, Wpost1, out);
  }
  k_stats<<<512, 256, 0, stream>>>(out, eidx, batch, stats);
  k_norm<<<nblk16, 256, 0, stream>>>(edge_fea, eidx, batch, stats,
                                     gamma_s, beta_s, gamma_v, out);
}